// Round 1
// baseline (589.333 us; speedup 1.0000x reference)
//
#include <hip/hip_runtime.h>
#include <math.h>

// Problem shape (fixed by setup_inputs):
//   x:            [N=2, C=4, D=64, H=128, W=128] f32
//   kernel_sizes: [N=2, D=64, H=128, W=128, 3]   f32
//   out:          [N, C, D, H, W] f32
constexpr int N = 2, C = 4, D = 64, H = 128, W = 128;
constexpr int HW  = H * W;        // 16384
constexpr int DHW = D * H * W;    // 1048576 (= 2^20)
constexpr int NC  = N * C;        // 8
constexpr int RED_BLOCKS = 64;    // partial-reduce blocks per (n,c)
constexpr float EPSf = 1e-5f;

// ws layout (floats):
//   [0, NC*DHW)                : SAT (33.55 MB)
//   psum: NC*RED_BLOCKS
//   psq : NC*RED_BLOCKS
//   stats: mean[NC], std[NC], invstd[NC]
// total ~33.56 MB

// ---------------- Kernel 1a: partial sums for mean/std ----------------
__global__ __launch_bounds__(256) void k_reduce(const float* __restrict__ x,
                                                float* __restrict__ psum,
                                                float* __restrict__ psq) {
    const int b  = blockIdx.x;            // nc*RED_BLOCKS + rb
    const int nc = b / RED_BLOCKS;
    const int rb = b % RED_BLOCKS;
    constexpr int CHUNK = DHW / RED_BLOCKS;   // 16384
    const float* p = x + (size_t)nc * DHW + (size_t)rb * CHUNK;
    float s = 0.f, q = 0.f;
    for (int i = threadIdx.x; i < CHUNK; i += 256) {
        float v = p[i];
        s += v; q += v * v;
    }
    #pragma unroll
    for (int off = 32; off; off >>= 1) {
        s += __shfl_down(s, off, 64);
        q += __shfl_down(q, off, 64);
    }
    __shared__ float ss[4], sq[4];
    const int w = threadIdx.x >> 6, lane = threadIdx.x & 63;
    if (lane == 0) { ss[w] = s; sq[w] = q; }
    __syncthreads();
    if (threadIdx.x == 0) {
        psum[b] = ss[0] + ss[1] + ss[2] + ss[3];
        psq[b]  = sq[0] + sq[1] + sq[2] + sq[3];
    }
}

// ---------------- Kernel 1b: finalize mean/std (double, deterministic) ----------------
__global__ __launch_bounds__(64) void k_stats(const float* __restrict__ psum,
                                              const float* __restrict__ psq,
                                              float* __restrict__ stats) {
    const int nc = blockIdx.x;
    const int t  = threadIdx.x;          // 64 threads = RED_BLOCKS
    double s = (double)psum[nc * RED_BLOCKS + t];
    double q = (double)psq[nc * RED_BLOCKS + t];
    #pragma unroll
    for (int off = 32; off; off >>= 1) {
        s += __shfl_down(s, off, 64);
        q += __shfl_down(q, off, 64);
    }
    if (t == 0) {
        const double M = (double)DHW;
        double mean = s / M;
        double var  = (q - s * s / M) / (M - 1.0);   // torch ddof=1
        float stdv  = (float)sqrt(var);
        stats[nc]          = (float)mean;
        stats[NC + nc]     = stdv;
        stats[2 * NC + nc] = 1.0f / (stdv + EPSf);
    }
}

// ---------------- Kernel 2: per-z-slice normalized 2D SAT ----------------
// 64 KB LDS tile, XOR swizzle (x ^ (y&31)) -> both row scans (lane=y) and
// column scans (lane=x) hit 32 distinct banks (2 lanes/bank = free).
__global__ __launch_bounds__(256) void k_sat2d(const float* __restrict__ x,
                                               const float* __restrict__ stats,
                                               float* __restrict__ sat) {
    __shared__ float tile[H * W];          // 65536 B
    const int slice = blockIdx.x;          // nc*D + z
    const int nc = slice / D;
    const float mean = stats[nc];
    const float inv  = stats[2 * NC + nc];
    const float* src = x   + (size_t)slice * HW;
    float*       dst = sat + (size_t)slice * HW;

    for (int i = threadIdx.x; i < HW; i += 256) {
        int y = i >> 7, xx = i & 127;
        tile[(y << 7) + (xx ^ (y & 31))] = (src[i] - mean) * inv;
    }
    __syncthreads();
    // row scan: thread t scans row t (x-direction)
    if (threadIdx.x < H) {
        const int y = threadIdx.x;
        const int base = y << 7, sw = y & 31;
        float run = 0.f;
        for (int i = 0; i < W; ++i) {
            int a = base + (i ^ sw);
            run += tile[a];
            tile[a] = run;
        }
    }
    __syncthreads();
    // column scan: thread t scans column t (y-direction)
    if (threadIdx.x < W) {
        const int xx = threadIdx.x;
        float run = 0.f;
        for (int y = 0; y < H; ++y) {
            int a = (y << 7) + (xx ^ (y & 31));
            run += tile[a];
            tile[a] = run;
        }
    }
    __syncthreads();
    for (int i = threadIdx.x; i < HW; i += 256) {
        int y = i >> 7, xx = i & 127;
        dst[i] = tile[(y << 7) + (xx ^ (y & 31))];
    }
}

// ---------------- Kernel 3: cumsum along z (finishes 3D SAT) ----------------
__global__ __launch_bounds__(128) void k_satz(float* __restrict__ sat) {
    const int b  = blockIdx.x;         // nc*H + y
    const int nc = b / H, y = b % H;
    float* p = sat + (size_t)nc * DHW + (size_t)y * W + threadIdx.x;
    float run = 0.f;
    for (int z = 0; z < D; ++z) {
        run += p[(size_t)z * HW];
        p[(size_t)z * HW] = run;
    }
}

// ---------------- Kernel 4: factorized 8-corner box sample ----------------
// 4 signed taps/dim: minus-corner taps carry weight -(1-f),-f; plus-corner
// taps +(1-f),+f. Triple product over dims reproduces all 8 corners with
// coeff = product of signs.
__device__ __forceinline__ void taps4(float g, float K, float last, int lastI,
                                      int* idx, float* wt) {
    float c  = g - K;
    float ix = fminf(fmaxf((c + 1.0f) * 0.5f * last, 0.0f), last);
    float fl = floorf(ix);
    int   i0 = (int)fl;
    float f  = ix - fl;
    idx[0] = i0; idx[1] = min(i0 + 1, lastI);
    wt[0] = -(1.0f - f); wt[1] = -f;
    c  = g + K;
    ix = fminf(fmaxf((c + 1.0f) * 0.5f * last, 0.0f), last);
    fl = floorf(ix);
    i0 = (int)fl;
    f  = ix - fl;
    idx[2] = i0; idx[3] = min(i0 + 1, lastI);
    wt[2] = 1.0f - f; wt[3] = f;
}

__global__ __launch_bounds__(256) void k_sample(const float* __restrict__ sat,
                                                const float* __restrict__ ks,
                                                const float* __restrict__ stats,
                                                float* __restrict__ out) {
    const int t = blockIdx.x * 256 + threadIdx.x;   // linear over (n,z,y,x)
    const int x = t & (W - 1);
    const int y = (t >> 7) & (H - 1);
    const int z = (t >> 14) & (D - 1);
    const int n = t >> 20;

    const float* kp = ks + (size_t)t * 3;
    const float k0 = kp[0], k1 = kp[1], k2 = kp[2];

    const float gx = -1.0f + (float)x * (2.0f / 127.0f) - (1.0f / 128.0f);
    const float gy = -1.0f + (float)y * (2.0f / 127.0f) - (1.0f / 128.0f);
    const float gz = -1.0f + (float)z * (2.0f / 63.0f)  - (1.0f / 64.0f);

    int xi[4], yi[4], zi[4];
    float wx[4], wy[4], wz[4];
    taps4(gx, k0 * (1.0f / 128.0f), 127.0f, 127, xi, wx);
    taps4(gy, k1 * (1.0f / 128.0f), 127.0f, 127, yi, wy);
    taps4(gz, k2 * (1.0f / 64.0f),   63.0f,  63, zi, wz);

    const float* b0 = sat + (size_t)n * C * DHW;
    float acc0 = 0.f, acc1 = 0.f, acc2 = 0.f, acc3 = 0.f;
    #pragma unroll
    for (int v = 0; v < 4; ++v) {
        const int   zb  = zi[v] * HW;
        const float wzv = wz[v];
        #pragma unroll
        for (int u = 0; u < 4; ++u) {
            const int rb = zb + yi[u] * W;
            float s0 = 0.f, s1 = 0.f, s2 = 0.f, s3 = 0.f;
            #pragma unroll
            for (int q = 0; q < 4; ++q) {
                const int idx = rb + xi[q];
                const float wq = wx[q];
                s0 += wq * b0[idx];
                s1 += wq * b0[idx + DHW];
                s2 += wq * b0[idx + 2 * DHW];
                s3 += wq * b0[idx + 3 * DHW];
            }
            const float wvu = wzv * wy[u];
            acc0 += wvu * s0; acc1 += wvu * s1;
            acc2 += wvu * s2; acc3 += wvu * s3;
        }
    }

    const float inva = 1.0f / (k0 * k1 * k2 + EPSf);
    const int spatial = t & (DHW - 1);
    float* po = out + (size_t)n * C * DHW + spatial;
    po[0]       = acc0 * inva * stats[NC + n * C + 0] + stats[n * C + 0];
    po[DHW]     = acc1 * inva * stats[NC + n * C + 1] + stats[n * C + 1];
    po[2 * DHW] = acc2 * inva * stats[NC + n * C + 2] + stats[n * C + 2];
    po[3 * DHW] = acc3 * inva * stats[NC + n * C + 3] + stats[n * C + 3];
}

extern "C" void kernel_launch(void* const* d_in, const int* in_sizes, int n_in,
                              void* d_out, int out_size, void* d_ws, size_t ws_size,
                              hipStream_t stream) {
    const float* x  = (const float*)d_in[0];
    const float* ks = (const float*)d_in[1];
    float* out = (float*)d_out;
    float* ws  = (float*)d_ws;

    float* sat   = ws;                               // NC*DHW floats
    float* psum  = ws + (size_t)NC * DHW;            // NC*RED_BLOCKS
    float* psq   = psum + NC * RED_BLOCKS;           // NC*RED_BLOCKS
    float* stats = psq + NC * RED_BLOCKS;            // 3*NC

    k_reduce<<<NC * RED_BLOCKS, 256, 0, stream>>>(x, psum, psq);
    k_stats <<<NC, 64, 0, stream>>>(psum, psq, stats);
    k_sat2d <<<NC * D, 256, 0, stream>>>(x, stats, sat);
    k_satz  <<<NC * H, 128, 0, stream>>>(sat);
    k_sample<<<(N * DHW) / 256, 256, 0, stream>>>(sat, ks, stats, out);
}

// Round 2
// 292.632 us; speedup vs baseline: 2.0139x; 2.0139x over previous
//
#include <hip/hip_runtime.h>
#include <math.h>

// Problem shape (fixed by setup_inputs):
//   x:            [N=2, C=4, D=64, H=128, W=128] f32
//   kernel_sizes: [N=2, D=64, H=128, W=128, 3]   f32
//   out:          [N, C, D, H, W] f32
constexpr int N = 2, C = 4, D = 64, H = 128, W = 128;
constexpr int HW  = H * W;        // 16384
constexpr int DHW = D * H * W;    // 1048576 (= 2^20)
constexpr int NC  = N * C;        // 8
constexpr int RED_BLOCKS = 64;
constexpr float EPSf = 1e-5f;

// ws layout (floats):
//   [0, NC*DHW)  : SAT, channel-interleaved [n][z][y][x][c4]  (33.55 MB)
//   psum: NC*RED_BLOCKS ; psq: NC*RED_BLOCKS ; stats: 3*NC

__device__ __forceinline__ void fma4(float4& a, float w, const float4& b) {
    a.x += w * b.x; a.y += w * b.y; a.z += w * b.z; a.w += w * b.w;
}

// ---------------- Kernel 1a: partial sums for mean/std ----------------
__global__ __launch_bounds__(256) void k_reduce(const float* __restrict__ x,
                                                float* __restrict__ psum,
                                                float* __restrict__ psq) {
    const int b  = blockIdx.x;
    const int nc = b / RED_BLOCKS;
    const int rb = b % RED_BLOCKS;
    constexpr int CHUNK = DHW / RED_BLOCKS;
    const float* p = x + (size_t)nc * DHW + (size_t)rb * CHUNK;
    float s = 0.f, q = 0.f;
    for (int i = threadIdx.x; i < CHUNK; i += 256) {
        float v = p[i];
        s += v; q += v * v;
    }
    #pragma unroll
    for (int off = 32; off; off >>= 1) {
        s += __shfl_down(s, off, 64);
        q += __shfl_down(q, off, 64);
    }
    __shared__ float ss[4], sq[4];
    const int w = threadIdx.x >> 6, lane = threadIdx.x & 63;
    if (lane == 0) { ss[w] = s; sq[w] = q; }
    __syncthreads();
    if (threadIdx.x == 0) {
        psum[b] = ss[0] + ss[1] + ss[2] + ss[3];
        psq[b]  = sq[0] + sq[1] + sq[2] + sq[3];
    }
}

// ---------------- Kernel 1b: finalize mean/std ----------------
__global__ __launch_bounds__(64) void k_stats(const float* __restrict__ psum,
                                              const float* __restrict__ psq,
                                              float* __restrict__ stats) {
    const int nc = blockIdx.x;
    const int t  = threadIdx.x;
    double s = (double)psum[nc * RED_BLOCKS + t];
    double q = (double)psq[nc * RED_BLOCKS + t];
    #pragma unroll
    for (int off = 32; off; off >>= 1) {
        s += __shfl_down(s, off, 64);
        q += __shfl_down(q, off, 64);
    }
    if (t == 0) {
        const double M = (double)DHW;
        double mean = s / M;
        double var  = (q - s * s / M) / (M - 1.0);
        float stdv  = (float)sqrt(var);
        stats[nc]          = (float)mean;
        stats[NC + nc]     = stdv;
        stats[2 * NC + nc] = 1.0f / (stdv + EPSf);
    }
}

// ---------------- Kernel 2: per-z-slice normalized 2D SAT ----------------
// LDS tile with XOR swizzle; writes channel-interleaved (stride-16B scalars).
// The 4 channel-writers of a given line have block IDs 64 apart -> same XCD
// under round-robin -> L2 merges partial lines.
__global__ __launch_bounds__(256) void k_sat2d(const float* __restrict__ x,
                                               const float* __restrict__ stats,
                                               float* __restrict__ sat) {
    __shared__ float tile[H * W];          // 65536 B
    const int slice = blockIdx.x;          // nc*D + z
    const int nc = slice / D;
    const int z  = slice % D;
    const int n  = nc / C;
    const int c  = nc % C;
    const float mean = stats[nc];
    const float inv  = stats[2 * NC + nc];
    const float* src = x + (size_t)slice * HW;

    for (int i = threadIdx.x; i < HW; i += 256) {
        int y = i >> 7, xx = i & 127;
        tile[(y << 7) + (xx ^ (y & 31))] = (src[i] - mean) * inv;
    }
    __syncthreads();
    if (threadIdx.x < H) {      // row scan (x)
        const int y = threadIdx.x;
        const int base = y << 7, sw = y & 31;
        float run = 0.f;
        for (int i = 0; i < W; ++i) {
            int a = base + (i ^ sw);
            run += tile[a];
            tile[a] = run;
        }
    }
    __syncthreads();
    if (threadIdx.x < W) {      // column scan (y)
        const int xx = threadIdx.x;
        float run = 0.f;
        for (int y = 0; y < H; ++y) {
            int a = (y << 7) + (xx ^ (y & 31));
            run += tile[a];
            tile[a] = run;
        }
    }
    __syncthreads();
    float* dst = sat + ((size_t)(n * D + z) * HW) * 4 + c;
    for (int i = threadIdx.x; i < HW; i += 256) {
        int y = i >> 7, xx = i & 127;
        dst[(size_t)i * 4] = tile[(y << 7) + (xx ^ (y & 31))];
    }
}

// ---------------- Kernel 3: z-cumsum on interleaved SAT ----------------
// 4 independent (n,y)-row chains per thread for latency hiding.
__global__ __launch_bounds__(128) void k_satz(float4* __restrict__ sat) {
    const int g = blockIdx.x;            // 64 groups of 4 rows (row = n*H + y)
    const int x = threadIdx.x;
    const int r0 = g * 4;
    // rows r0..r0+3 share n (H divisible by 4)
    const int n = r0 >> 7;
    const int y0 = r0 & 127;
    float4* p0 = sat + (size_t)n * DHW + (size_t)(y0 + 0) * W + x;
    float4* p1 = sat + (size_t)n * DHW + (size_t)(y0 + 1) * W + x;
    float4* p2 = sat + (size_t)n * DHW + (size_t)(y0 + 2) * W + x;
    float4* p3 = sat + (size_t)n * DHW + (size_t)(y0 + 3) * W + x;
    float4 r0v = {0,0,0,0}, r1v = {0,0,0,0}, r2v = {0,0,0,0}, r3v = {0,0,0,0};
    for (int z = 0; z < D; ++z) {
        const size_t off = (size_t)z * HW;
        float4 a0 = p0[off], a1 = p1[off], a2 = p2[off], a3 = p3[off];
        r0v.x += a0.x; r0v.y += a0.y; r0v.z += a0.z; r0v.w += a0.w;
        r1v.x += a1.x; r1v.y += a1.y; r1v.z += a1.z; r1v.w += a1.w;
        r2v.x += a2.x; r2v.y += a2.y; r2v.z += a2.z; r2v.w += a2.w;
        r3v.x += a3.x; r3v.y += a3.y; r3v.z += a3.z; r3v.w += a3.w;
        p0[off] = r0v; p1[off] = r1v; p2[off] = r2v; p3[off] = r3v;
    }
}

// ---------------- Kernel 4: factorized 8-corner box sample ----------------
__device__ __forceinline__ void taps4(float g, float K, float last, int lastI,
                                      int* idx, float* wt) {
    float c  = g - K;
    float ix = fminf(fmaxf((c + 1.0f) * 0.5f * last, 0.0f), last);
    float fl = floorf(ix);
    int   i0 = (int)fl;
    float f  = ix - fl;
    idx[0] = i0; idx[1] = min(i0 + 1, lastI);
    wt[0] = -(1.0f - f); wt[1] = -f;
    c  = g + K;
    ix = fminf(fmaxf((c + 1.0f) * 0.5f * last, 0.0f), last);
    fl = floorf(ix);
    i0 = (int)fl;
    f  = ix - fl;
    idx[2] = i0; idx[3] = min(i0 + 1, lastI);
    wt[2] = 1.0f - f; wt[3] = f;
}

__global__ __launch_bounds__(256) void k_sample(const float4* __restrict__ sat,
                                                const float* __restrict__ ks,
                                                const float* __restrict__ stats,
                                                float* __restrict__ out) {
    // XCD-contiguous swizzle: 8192 blocks, 1024 per XCD
    const int bid  = (blockIdx.x & 7) * 1024 + (blockIdx.x >> 3);
    const int t = bid * 256 + threadIdx.x;       // linear over (n,z,y,x)
    const int x = t & (W - 1);
    const int y = (t >> 7) & (H - 1);
    const int z = (t >> 14) & (D - 1);
    const int n = t >> 20;

    const float* kp = ks + (size_t)t * 3;
    const float k0 = kp[0], k1 = kp[1], k2 = kp[2];

    const float gx = -1.0f + (float)x * (2.0f / 127.0f) - (1.0f / 128.0f);
    const float gy = -1.0f + (float)y * (2.0f / 127.0f) - (1.0f / 128.0f);
    const float gz = -1.0f + (float)z * (2.0f / 63.0f)  - (1.0f / 64.0f);

    int xi[4], yi[4], zi[4];
    float wx[4], wy[4], wz[4];
    taps4(gx, k0 * (1.0f / 128.0f), 127.0f, 127, xi, wx);
    taps4(gy, k1 * (1.0f / 128.0f), 127.0f, 127, yi, wy);
    taps4(gz, k2 * (1.0f / 64.0f),   63.0f,  63, zi, wz);

    const float4* b4 = sat + (size_t)n * DHW;
    float4 acc = {0, 0, 0, 0};
    #pragma unroll
    for (int v = 0; v < 4; ++v) {
        const int   zb  = zi[v] * HW;
        const float wzv = wz[v];
        #pragma unroll
        for (int u = 0; u < 4; ++u) {
            const int rb = zb + yi[u] * W;
            float4 s = {0, 0, 0, 0};
            fma4(s, wx[0], b4[rb + xi[0]]);
            fma4(s, wx[1], b4[rb + xi[1]]);
            fma4(s, wx[2], b4[rb + xi[2]]);
            fma4(s, wx[3], b4[rb + xi[3]]);
            fma4(acc, wzv * wy[u], s);
        }
    }

    const float inva = 1.0f / (k0 * k1 * k2 + EPSf);
    const int spatial = t & (DHW - 1);
    float* po = out + (size_t)n * C * DHW + spatial;
    const int sb = n * C;
    po[0]       = acc.x * inva * stats[NC + sb + 0] + stats[sb + 0];
    po[DHW]     = acc.y * inva * stats[NC + sb + 1] + stats[sb + 1];
    po[2 * DHW] = acc.z * inva * stats[NC + sb + 2] + stats[sb + 2];
    po[3 * DHW] = acc.w * inva * stats[NC + sb + 3] + stats[sb + 3];
}

extern "C" void kernel_launch(void* const* d_in, const int* in_sizes, int n_in,
                              void* d_out, int out_size, void* d_ws, size_t ws_size,
                              hipStream_t stream) {
    const float* x  = (const float*)d_in[0];
    const float* ks = (const float*)d_in[1];
    float* out = (float*)d_out;
    float* ws  = (float*)d_ws;

    float* sat   = ws;                               // NC*DHW floats (interleaved)
    float* psum  = ws + (size_t)NC * DHW;
    float* psq   = psum + NC * RED_BLOCKS;
    float* stats = psq + NC * RED_BLOCKS;

    k_reduce<<<NC * RED_BLOCKS, 256, 0, stream>>>(x, psum, psq);
    k_stats <<<NC, 64, 0, stream>>>(psum, psq, stats);
    k_sat2d <<<NC * D, 256, 0, stream>>>(x, stats, sat);
    k_satz  <<<(N * H) / 4, 128, 0, stream>>>((float4*)sat);
    k_sample<<<(N * DHW) / 256, 256, 0, stream>>>((const float4*)sat, ks, stats, out);
}

// Round 3
// 196.806 us; speedup vs baseline: 2.9945x; 1.4869x over previous
//
#include <hip/hip_runtime.h>
#include <math.h>

// Problem shape (fixed by setup_inputs):
//   x:            [N=2, C=4, D=64, H=128, W=128] f32
//   kernel_sizes: [N=2, D=64, H=128, W=128, 3]   f32
//   out:          [N, C, D, H, W] f32
constexpr int N = 2, C = 4, D = 64, H = 128, W = 128;
constexpr int HW  = H * W;        // 16384
constexpr int DHW = D * H * W;    // 1048576 (= 2^20)
constexpr int NC  = N * C;        // 8
constexpr int RED_BLOCKS = 64;
constexpr float EPSf = 1e-5f;

// ws layout (floats):
//   [0, NC*DHW)  : SAT, channel-interleaved [n][z][y][x][c4]  (33.55 MB)
//   psum: NC*RED_BLOCKS ; psq: NC*RED_BLOCKS ; stats: 3*NC

__device__ __forceinline__ void fma4(float4& a, float w, const float4& b) {
    a.x += w * b.x; a.y += w * b.y; a.z += w * b.z; a.w += w * b.w;
}

// ---------------- Kernel 1a: partial sums for mean/std ----------------
__global__ __launch_bounds__(256) void k_reduce(const float* __restrict__ x,
                                                float* __restrict__ psum,
                                                float* __restrict__ psq) {
    const int b  = blockIdx.x;
    const int nc = b / RED_BLOCKS;
    const int rb = b % RED_BLOCKS;
    constexpr int CHUNK = DHW / RED_BLOCKS;
    const float* p = x + (size_t)nc * DHW + (size_t)rb * CHUNK;
    float s = 0.f, q = 0.f;
    for (int i = threadIdx.x; i < CHUNK; i += 256) {
        float v = p[i];
        s += v; q += v * v;
    }
    #pragma unroll
    for (int off = 32; off; off >>= 1) {
        s += __shfl_down(s, off, 64);
        q += __shfl_down(q, off, 64);
    }
    __shared__ float ss[4], sq[4];
    const int w = threadIdx.x >> 6, lane = threadIdx.x & 63;
    if (lane == 0) { ss[w] = s; sq[w] = q; }
    __syncthreads();
    if (threadIdx.x == 0) {
        psum[b] = ss[0] + ss[1] + ss[2] + ss[3];
        psq[b]  = sq[0] + sq[1] + sq[2] + sq[3];
    }
}

// ---------------- Kernel 1b: finalize mean/std ----------------
__global__ __launch_bounds__(64) void k_stats(const float* __restrict__ psum,
                                              const float* __restrict__ psq,
                                              float* __restrict__ stats) {
    const int nc = blockIdx.x;
    const int t  = threadIdx.x;
    double s = (double)psum[nc * RED_BLOCKS + t];
    double q = (double)psq[nc * RED_BLOCKS + t];
    #pragma unroll
    for (int off = 32; off; off >>= 1) {
        s += __shfl_down(s, off, 64);
        q += __shfl_down(q, off, 64);
    }
    if (t == 0) {
        const double M = (double)DHW;
        double mean = s / M;
        double var  = (q - s * s / M) / (M - 1.0);
        float stdv  = (float)sqrt(var);
        stats[nc]          = (float)mean;
        stats[NC + nc]     = stdv;
        stats[2 * NC + nc] = 1.0f / (stdv + EPSf);
    }
}

// ---------------- Kernel 2: per-z-slice normalized 2D SAT ----------------
__global__ __launch_bounds__(256) void k_sat2d(const float* __restrict__ x,
                                               const float* __restrict__ stats,
                                               float* __restrict__ sat) {
    __shared__ float tile[H * W];          // 65536 B
    const int slice = blockIdx.x;          // nc*D + z
    const int nc = slice / D;
    const int z  = slice % D;
    const int n  = nc / C;
    const int c  = nc % C;
    const float mean = stats[nc];
    const float inv  = stats[2 * NC + nc];
    const float* src = x + (size_t)slice * HW;

    for (int i = threadIdx.x; i < HW; i += 256) {
        int y = i >> 7, xx = i & 127;
        tile[(y << 7) + (xx ^ (y & 31))] = (src[i] - mean) * inv;
    }
    __syncthreads();
    if (threadIdx.x < H) {      // row scan (x)
        const int y = threadIdx.x;
        const int base = y << 7, sw = y & 31;
        float run = 0.f;
        for (int i = 0; i < W; ++i) {
            int a = base + (i ^ sw);
            run += tile[a];
            tile[a] = run;
        }
    }
    __syncthreads();
    if (threadIdx.x < W) {      // column scan (y)
        const int xx = threadIdx.x;
        float run = 0.f;
        for (int y = 0; y < H; ++y) {
            int a = (y << 7) + (xx ^ (y & 31));
            run += tile[a];
            tile[a] = run;
        }
    }
    __syncthreads();
    float* dst = sat + ((size_t)(n * D + z) * HW) * 4 + c;
    for (int i = threadIdx.x; i < HW; i += 256) {
        int y = i >> 7, xx = i & 127;
        dst[(size_t)i * 4] = tile[(y << 7) + (xx ^ (y & 31))];
    }
}

// ---------------- Kernel 3: z-cumsum on interleaved SAT ----------------
__global__ __launch_bounds__(128) void k_satz(float4* __restrict__ sat) {
    const int g = blockIdx.x;            // 64 groups of 4 rows (row = n*H + y)
    const int x = threadIdx.x;
    const int r0 = g * 4;
    const int n = r0 >> 7;
    const int y0 = r0 & 127;
    float4* p0 = sat + (size_t)n * DHW + (size_t)(y0 + 0) * W + x;
    float4* p1 = sat + (size_t)n * DHW + (size_t)(y0 + 1) * W + x;
    float4* p2 = sat + (size_t)n * DHW + (size_t)(y0 + 2) * W + x;
    float4* p3 = sat + (size_t)n * DHW + (size_t)(y0 + 3) * W + x;
    float4 r0v = {0,0,0,0}, r1v = {0,0,0,0}, r2v = {0,0,0,0}, r3v = {0,0,0,0};
    for (int z = 0; z < D; ++z) {
        const size_t off = (size_t)z * HW;
        float4 a0 = p0[off], a1 = p1[off], a2 = p2[off], a3 = p3[off];
        r0v.x += a0.x; r0v.y += a0.y; r0v.z += a0.z; r0v.w += a0.w;
        r1v.x += a1.x; r1v.y += a1.y; r1v.z += a1.z; r1v.w += a1.w;
        r2v.x += a2.x; r2v.y += a2.y; r2v.z += a2.z; r2v.w += a2.w;
        r3v.x += a3.x; r3v.y += a3.y; r3v.z += a3.z; r3v.w += a3.w;
        p0[off] = r0v; p1[off] = r1v; p2[off] = r2v; p3[off] = r3v;
    }
}

// ---------------- Kernel 4: quad-per-voxel factorized box sample ----------------
// 4 lanes per voxel, one x-tap each. Quad lanes share the same (zi,yi) row for
// every (v,u) iteration -> their 4 addresses (xm, xm+1, xp, xp+1) coalesce into
// ~2.3 cache lines instead of 4, attacking the L1 line-access bound.
__device__ __forceinline__ void taps4(float g, float K, float scale, int lastI,
                                      int* idx, float* wt) {
    float c  = g - K;
    float ix = fminf(fmaxf((c + 1.0f) * scale, 0.0f), (float)lastI);
    float fl = floorf(ix);
    int   i0 = (int)fl;
    float f  = ix - fl;
    idx[0] = i0; idx[1] = min(i0 + 1, lastI);
    wt[0] = -(1.0f - f); wt[1] = -f;
    c  = g + K;
    ix = fminf(fmaxf((c + 1.0f) * scale, 0.0f), (float)lastI);
    fl = floorf(ix);
    i0 = (int)fl;
    f  = ix - fl;
    idx[2] = i0; idx[3] = min(i0 + 1, lastI);
    wt[2] = 1.0f - f; wt[3] = f;
}

__global__ __launch_bounds__(256) void k_sample(const float4* __restrict__ sat,
                                                const float* __restrict__ ks,
                                                const float* __restrict__ stats,
                                                float* __restrict__ out) {
    // 32768 blocks -> XCD-contiguous swizzle (4096 per XCD)
    const int bid = (blockIdx.x & 7) * 4096 + (blockIdx.x >> 3);
    const int tid = bid * 256 + (int)threadIdx.x;
    const int q   = tid & 3;          // x-tap index
    const int t   = tid >> 2;         // voxel linear over (n,z,y,x)
    const int x = t & (W - 1);
    const int y = (t >> 7) & (H - 1);
    const int z = (t >> 14) & (D - 1);
    const int n = t >> 20;

    const float* kp = ks + (size_t)t * 3;
    const float k0 = kp[0], k1 = kp[1], k2 = kp[2];

    const float gx = -1.0f + (float)x * (2.0f / 127.0f) - (1.0f / 128.0f);
    const float gy = -1.0f + (float)y * (2.0f / 127.0f) - (1.0f / 128.0f);
    const float gz = -1.0f + (float)z * (2.0f / 63.0f)  - (1.0f / 64.0f);

    int yi[4], zi[4];
    float wy[4], wz[4];
    taps4(gy, k1 * (1.0f / 128.0f), 63.5f, 127, yi, wy);
    taps4(gz, k2 * (1.0f / 64.0f),  31.5f,  63, zi, wz);

    // this lane's x tap
    const float Kx = k0 * (1.0f / 128.0f);
    const float cx = (q < 2) ? (gx - Kx) : (gx + Kx);
    float ix = fminf(fmaxf((cx + 1.0f) * 63.5f, 0.0f), 127.0f);
    float fl = floorf(ix);
    int   i0 = (int)fl;
    float f  = ix - fl;
    const int   xi = (q & 1) ? min(i0 + 1, 127) : i0;
    float wq = (q & 1) ? f : (1.0f - f);
    if (q < 2) wq = -wq;

    const float4* b4 = sat + (size_t)n * DHW + xi;
    float4 acc = {0, 0, 0, 0};
    #pragma unroll
    for (int v = 0; v < 4; ++v) {
        const int   zb  = zi[v] * HW;
        const float wzv = wz[v];
        #pragma unroll
        for (int u = 0; u < 4; ++u) {
            fma4(acc, wzv * wy[u], b4[zb + yi[u] * W]);
        }
    }
    acc.x *= wq; acc.y *= wq; acc.z *= wq; acc.w *= wq;

    // quad butterfly: all 4 lanes end with the full 64-tap sum
    #pragma unroll
    for (int m = 1; m <= 2; m <<= 1) {
        acc.x += __shfl_xor(acc.x, m, 64);
        acc.y += __shfl_xor(acc.y, m, 64);
        acc.z += __shfl_xor(acc.z, m, 64);
        acc.w += __shfl_xor(acc.w, m, 64);
    }

    const float inva = 1.0f / (k0 * k1 * k2 + EPSf);
    const float comp = (q == 0) ? acc.x : (q == 1) ? acc.y : (q == 2) ? acc.z : acc.w;
    const int   sb   = n * C + q;     // lane q writes channel q
    out[(size_t)sb * DHW + (t & (DHW - 1))] = comp * inva * stats[NC + sb] + stats[sb];
}

extern "C" void kernel_launch(void* const* d_in, const int* in_sizes, int n_in,
                              void* d_out, int out_size, void* d_ws, size_t ws_size,
                              hipStream_t stream) {
    const float* x  = (const float*)d_in[0];
    const float* ks = (const float*)d_in[1];
    float* out = (float*)d_out;
    float* ws  = (float*)d_ws;

    float* sat   = ws;                               // NC*DHW floats (interleaved)
    float* psum  = ws + (size_t)NC * DHW;
    float* psq   = psum + NC * RED_BLOCKS;
    float* stats = psq + NC * RED_BLOCKS;

    k_reduce<<<NC * RED_BLOCKS, 256, 0, stream>>>(x, psum, psq);
    k_stats <<<NC, 64, 0, stream>>>(psum, psq, stats);
    k_sat2d <<<NC * D, 256, 0, stream>>>(x, stats, sat);
    k_satz  <<<(N * H) / 4, 128, 0, stream>>>((float4*)sat);
    k_sample<<<(N * DHW * 4) / 256, 256, 0, stream>>>((const float4*)sat, ks, stats, out);
}

// Round 4
// 159.916 us; speedup vs baseline: 3.6853x; 1.2307x over previous
//
#include <hip/hip_runtime.h>
#include <math.h>

// Problem shape (fixed by setup_inputs):
//   x:            [N=2, C=4, D=64, H=128, W=128] f32
//   kernel_sizes: [N=2, D=64, H=128, W=128, 3]   f32
//   out:          [N, C, D, H, W] f32
constexpr int N = 2, C = 4, D = 64, H = 128, W = 128;
constexpr int HW  = H * W;        // 16384
constexpr int DHW = D * H * W;    // 1048576
constexpr int NC  = N * C;        // 8
constexpr int RED_BLOCKS = 64;
constexpr float EPSf = 1e-5f;

// k_sample tile geometry: 8x8x2 voxels, taps span [x-5, x+4] per dim
constexpr int TX = 8, TY = 8, TZ = 2;
constexpr int RX = 17, RY = 17, RZ = 11;   // TX+9, TY+9, TZ+9
constexpr int RXY = RX * RY;               // 289
constexpr int RSLOTS = RXY * RZ;           // 3179
constexpr int RCHUNKS = 50;                // ceil(3179/64)
constexpr int RPAD = RCHUNKS * 64;         // 3200 float4 = 51.2 KB LDS

typedef const __attribute__((address_space(1))) void glb_void;
typedef __attribute__((address_space(3))) void lds_void;

__device__ __forceinline__ void fma4(float4& a, float w, const float4& b) {
    a.x += w * b.x; a.y += w * b.y; a.z += w * b.z; a.w += w * b.w;
}

// ---------------- Kernel 1a: partial sums for mean/std ----------------
__global__ __launch_bounds__(256) void k_reduce(const float* __restrict__ x,
                                                float* __restrict__ psum,
                                                float* __restrict__ psq) {
    const int b  = blockIdx.x;
    const int nc = b / RED_BLOCKS;
    const int rb = b % RED_BLOCKS;
    constexpr int CHUNK = DHW / RED_BLOCKS;
    const float* p = x + (size_t)nc * DHW + (size_t)rb * CHUNK;
    float s = 0.f, q = 0.f;
    for (int i = threadIdx.x; i < CHUNK; i += 256) {
        float v = p[i];
        s += v; q += v * v;
    }
    #pragma unroll
    for (int off = 32; off; off >>= 1) {
        s += __shfl_down(s, off, 64);
        q += __shfl_down(q, off, 64);
    }
    __shared__ float ss[4], sq[4];
    const int w = threadIdx.x >> 6, lane = threadIdx.x & 63;
    if (lane == 0) { ss[w] = s; sq[w] = q; }
    __syncthreads();
    if (threadIdx.x == 0) {
        psum[b] = ss[0] + ss[1] + ss[2] + ss[3];
        psq[b]  = sq[0] + sq[1] + sq[2] + sq[3];
    }
}

// ---------------- Kernel 1b: finalize mean/std ----------------
__global__ __launch_bounds__(64) void k_stats(const float* __restrict__ psum,
                                              const float* __restrict__ psq,
                                              float* __restrict__ stats) {
    const int nc = blockIdx.x;
    const int t  = threadIdx.x;
    double s = (double)psum[nc * RED_BLOCKS + t];
    double q = (double)psq[nc * RED_BLOCKS + t];
    #pragma unroll
    for (int off = 32; off; off >>= 1) {
        s += __shfl_down(s, off, 64);
        q += __shfl_down(q, off, 64);
    }
    if (t == 0) {
        const double M = (double)DHW;
        double mean = s / M;
        double var  = (q - s * s / M) / (M - 1.0);
        float stdv  = (float)sqrt(var);
        stats[nc]          = (float)mean;
        stats[NC + nc]     = stdv;
        stats[2 * NC + nc] = 1.0f / (stdv + EPSf);
    }
}

// ---------------- Kernel 2: per-z-slice normalized 2D SAT ----------------
__global__ __launch_bounds__(256) void k_sat2d(const float* __restrict__ x,
                                               const float* __restrict__ stats,
                                               float* __restrict__ sat) {
    __shared__ float tile[H * W];          // 65536 B
    const int slice = blockIdx.x;          // nc*D + z
    const int nc = slice / D;
    const int z  = slice % D;
    const int n  = nc / C;
    const int c  = nc % C;
    const float mean = stats[nc];
    const float inv  = stats[2 * NC + nc];
    const float* src = x + (size_t)slice * HW;

    for (int i = threadIdx.x; i < HW; i += 256) {
        int y = i >> 7, xx = i & 127;
        tile[(y << 7) + (xx ^ (y & 31))] = (src[i] - mean) * inv;
    }
    __syncthreads();
    if (threadIdx.x < H) {      // row scan (x)
        const int y = threadIdx.x;
        const int base = y << 7, sw = y & 31;
        float run = 0.f;
        for (int i = 0; i < W; ++i) {
            int a = base + (i ^ sw);
            run += tile[a];
            tile[a] = run;
        }
    }
    __syncthreads();
    if (threadIdx.x < W) {      // column scan (y)
        const int xx = threadIdx.x;
        float run = 0.f;
        for (int y = 0; y < H; ++y) {
            int a = (y << 7) + (xx ^ (y & 31));
            run += tile[a];
            tile[a] = run;
        }
    }
    __syncthreads();
    float* dst = sat + ((size_t)(n * D + z) * HW) * 4 + c;
    for (int i = threadIdx.x; i < HW; i += 256) {
        int y = i >> 7, xx = i & 127;
        dst[(size_t)i * 4] = tile[(y << 7) + (xx ^ (y & 31))];
    }
}

// ---------------- Kernel 3: z-cumsum on interleaved SAT ----------------
__global__ __launch_bounds__(128) void k_satz(float4* __restrict__ sat) {
    const int g = blockIdx.x;            // 64 groups of 4 rows (row = n*H + y)
    const int x = threadIdx.x;
    const int r0 = g * 4;
    const int n = r0 >> 7;
    const int y0 = r0 & 127;
    float4* p0 = sat + (size_t)n * DHW + (size_t)(y0 + 0) * W + x;
    float4* p1 = sat + (size_t)n * DHW + (size_t)(y0 + 1) * W + x;
    float4* p2 = sat + (size_t)n * DHW + (size_t)(y0 + 2) * W + x;
    float4* p3 = sat + (size_t)n * DHW + (size_t)(y0 + 3) * W + x;
    float4 r0v = {0,0,0,0}, r1v = {0,0,0,0}, r2v = {0,0,0,0}, r3v = {0,0,0,0};
    for (int z = 0; z < D; ++z) {
        const size_t off = (size_t)z * HW;
        float4 a0 = p0[off], a1 = p1[off], a2 = p2[off], a3 = p3[off];
        r0v.x += a0.x; r0v.y += a0.y; r0v.z += a0.z; r0v.w += a0.w;
        r1v.x += a1.x; r1v.y += a1.y; r1v.z += a1.z; r1v.w += a1.w;
        r2v.x += a2.x; r2v.y += a2.y; r2v.z += a2.z; r2v.w += a2.w;
        r3v.x += a3.x; r3v.y += a3.y; r3v.z += a3.z; r3v.w += a3.w;
        p0[off] = r0v; p1[off] = r1v; p2[off] = r2v; p3[off] = r3v;
    }
}

// ---------------- Kernel 4: LDS-staged quad-per-voxel box sample ----------------
__device__ __forceinline__ void taps4(float g, float K, float scale, int lastI,
                                      int* idx, float* wt) {
    float c  = g - K;
    float ix = fminf(fmaxf((c + 1.0f) * scale, 0.0f), (float)lastI);
    float fl = floorf(ix);
    int   i0 = (int)fl;
    float f  = ix - fl;
    idx[0] = i0; idx[1] = min(i0 + 1, lastI);
    wt[0] = -(1.0f - f); wt[1] = -f;
    c  = g + K;
    ix = fminf(fmaxf((c + 1.0f) * scale, 0.0f), (float)lastI);
    fl = floorf(ix);
    i0 = (int)fl;
    f  = ix - fl;
    idx[2] = i0; idx[3] = min(i0 + 1, lastI);
    wt[2] = 1.0f - f; wt[3] = f;
}

__global__ __launch_bounds__(256) void k_sample(const float4* __restrict__ sat,
                                                const float* __restrict__ ks,
                                                const float* __restrict__ stats,
                                                float* __restrict__ out) {
    __shared__ float4 tile[RPAD];          // 51.2 KB
    // 16384 blocks -> XCD-contiguous swizzle (2048 per XCD)
    const int bid = (blockIdx.x & 7) * 2048 + (blockIdx.x >> 3);
    const int tx = bid & 15, ty = (bid >> 4) & 15, tz = (bid >> 8) & 31;
    const int n  = bid >> 13;
    const int x0 = tx * TX, y0 = ty * TY, z0 = tz * TZ;
    const int rx0 = x0 - 5, ry0 = y0 - 5, rz0 = z0 - 5;

    const int lane = threadIdx.x & 63;
    const int wid  = threadIdx.x >> 6;
    const float4* satn = sat + (size_t)n * DHW;

    // ---- stage region into LDS: per-lane global src, linear LDS dest ----
    for (int chunk = wid; chunk < RCHUNKS; chunk += 4) {
        int idx  = chunk * 64 + lane;
        int cidx = min(idx, RSLOTS - 1);
        int rz  = cidx / RXY;
        int rem = cidx - rz * RXY;
        int ry  = rem / RX;
        int rx  = rem - ry * RX;
        int gz = min(max(rz0 + rz, 0), D - 1);
        int gy = min(max(ry0 + ry, 0), H - 1);
        int gx = min(max(rx0 + rx, 0), W - 1);
        const float4* src = satn + ((size_t)gz * HW + (size_t)gy * W + gx);
        __builtin_amdgcn_global_load_lds((glb_void*)src,
                                         (lds_void*)&tile[chunk * 64], 16, 0, 0);
    }
    __syncthreads();

    const int q   = threadIdx.x & 3;       // x-tap index
    const int qid = threadIdx.x >> 2;      // quad id within block

    #pragma unroll
    for (int p = 0; p < 2; ++p) {
        const int v = qid + p * 64;        // voxel within tile
        const int x = x0 + (v & 7);
        const int y = y0 + ((v >> 3) & 7);
        const int z = z0 + (v >> 6);

        const float* kp = ks + (size_t)(((n * D + z) * H + y) * W + x) * 3;
        const float k0 = kp[0], k1 = kp[1], k2 = kp[2];

        const float gx = -1.0f + (float)x * (2.0f / 127.0f) - (1.0f / 128.0f);
        const float gy = -1.0f + (float)y * (2.0f / 127.0f) - (1.0f / 128.0f);
        const float gz = -1.0f + (float)z * (2.0f / 63.0f)  - (1.0f / 64.0f);

        int yi[4], zi[4];
        float wy[4], wz[4];
        taps4(gy, k1 * (1.0f / 128.0f), 63.5f, 127, yi, wy);
        taps4(gz, k2 * (1.0f / 64.0f),  31.5f,  63, zi, wz);

        // this lane's x tap
        const float Kx = k0 * (1.0f / 128.0f);
        const float cx = (q < 2) ? (gx - Kx) : (gx + Kx);
        float ix = fminf(fmaxf((cx + 1.0f) * 63.5f, 0.0f), 127.0f);
        float fl = floorf(ix);
        int   i0 = (int)fl;
        float f  = ix - fl;
        const int xi = (q & 1) ? min(i0 + 1, 127) : i0;
        float wq = (q & 1) ? f : (1.0f - f);
        if (q < 2) wq = -wq;
        const int jx = xi - rx0;

        float4 acc = {0, 0, 0, 0};
        #pragma unroll
        for (int vv = 0; vv < 4; ++vv) {
            const int zb = (zi[vv] - rz0) * RXY + jx;
            const float wzv = wz[vv];
            #pragma unroll
            for (int u = 0; u < 4; ++u) {
                fma4(acc, wzv * wy[u], tile[zb + (yi[u] - ry0) * RX]);
            }
        }
        acc.x *= wq; acc.y *= wq; acc.z *= wq; acc.w *= wq;

        // quad butterfly: all 4 lanes end with the full 64-tap sum
        #pragma unroll
        for (int m = 1; m <= 2; m <<= 1) {
            acc.x += __shfl_xor(acc.x, m, 64);
            acc.y += __shfl_xor(acc.y, m, 64);
            acc.z += __shfl_xor(acc.z, m, 64);
            acc.w += __shfl_xor(acc.w, m, 64);
        }

        const float inva = 1.0f / (k0 * k1 * k2 + EPSf);
        const float comp = (q == 0) ? acc.x : (q == 1) ? acc.y : (q == 2) ? acc.z : acc.w;
        const int   sb   = n * C + q;      // lane q writes channel q
        out[(size_t)sb * DHW + (size_t)z * HW + y * W + x] =
            comp * inva * stats[NC + sb] + stats[sb];
    }
}

extern "C" void kernel_launch(void* const* d_in, const int* in_sizes, int n_in,
                              void* d_out, int out_size, void* d_ws, size_t ws_size,
                              hipStream_t stream) {
    const float* x  = (const float*)d_in[0];
    const float* ks = (const float*)d_in[1];
    float* out = (float*)d_out;
    float* ws  = (float*)d_ws;

    float* sat   = ws;                               // NC*DHW floats (interleaved)
    float* psum  = ws + (size_t)NC * DHW;
    float* psq   = psum + NC * RED_BLOCKS;
    float* stats = psq + NC * RED_BLOCKS;

    k_reduce<<<NC * RED_BLOCKS, 256, 0, stream>>>(x, psum, psq);
    k_stats <<<NC, 64, 0, stream>>>(psum, psq, stats);
    k_sat2d <<<NC * D, 256, 0, stream>>>(x, stats, sat);
    k_satz  <<<(N * H) / 4, 128, 0, stream>>>((float4*)sat);
    k_sample<<<16384, 256, 0, stream>>>((const float4*)sat, ks, stats, out);
}

// Round 5
// 126.294 us; speedup vs baseline: 4.6664x; 1.2662x over previous
//
#include <hip/hip_runtime.h>
#include <math.h>

// Problem shape (fixed by setup_inputs):
//   x:            [N=2, C=4, D=64, H=128, W=128] f32
//   kernel_sizes: [N=2, D=64, H=128, W=128, 3]   f32
//   out:          [N, C, D, H, W] f32
constexpr int N = 2, C = 4, D = 64, H = 128, W = 128;
constexpr int HW  = H * W;        // 16384
constexpr int DHW = D * H * W;    // 1048576
constexpr int NC  = N * C;        // 8
constexpr int RED_BLOCKS = 64;
constexpr float EPSf = 1e-5f;

// k_sample tile geometry: 16x16x4 voxels, taps span [x-5, x+4] per dim
constexpr int TX = 16, TY = 16, TZ = 4;
constexpr int RX = 25, RY = 25, RZ = 13;   // TX+9, TY+9, TZ+9
constexpr int RXY = RX * RY;               // 625
constexpr int RSLOTS = RXY * RZ;           // 8125
constexpr int RCHUNKS = 127;               // ceil(8125/64)
constexpr int RPAD = RCHUNKS * 64;         // 8128 float4 = 130048 B dynamic LDS

typedef const __attribute__((address_space(1))) void glb_void;
typedef __attribute__((address_space(3))) void lds_void;

__device__ __forceinline__ void fma4(float4& a, float w, const float4& b) {
    a.x += w * b.x; a.y += w * b.y; a.z += w * b.z; a.w += w * b.w;
}

// ---------------- Kernel 1a: partial sums for mean/std ----------------
__global__ __launch_bounds__(256) void k_reduce(const float* __restrict__ x,
                                                float* __restrict__ psum,
                                                float* __restrict__ psq) {
    const int b  = blockIdx.x;
    const int nc = b / RED_BLOCKS;
    const int rb = b % RED_BLOCKS;
    constexpr int CHUNK = DHW / RED_BLOCKS;
    const float* p = x + (size_t)nc * DHW + (size_t)rb * CHUNK;
    float s = 0.f, q = 0.f;
    for (int i = threadIdx.x; i < CHUNK; i += 256) {
        float v = p[i];
        s += v; q += v * v;
    }
    #pragma unroll
    for (int off = 32; off; off >>= 1) {
        s += __shfl_down(s, off, 64);
        q += __shfl_down(q, off, 64);
    }
    __shared__ float ss[4], sq[4];
    const int w = threadIdx.x >> 6, lane = threadIdx.x & 63;
    if (lane == 0) { ss[w] = s; sq[w] = q; }
    __syncthreads();
    if (threadIdx.x == 0) {
        psum[b] = ss[0] + ss[1] + ss[2] + ss[3];
        psq[b]  = sq[0] + sq[1] + sq[2] + sq[3];
    }
}

// ---------------- Kernel 1b: finalize mean/std ----------------
__global__ __launch_bounds__(64) void k_stats(const float* __restrict__ psum,
                                              const float* __restrict__ psq,
                                              float* __restrict__ stats) {
    const int nc = blockIdx.x;
    const int t  = threadIdx.x;
    double s = (double)psum[nc * RED_BLOCKS + t];
    double q = (double)psq[nc * RED_BLOCKS + t];
    #pragma unroll
    for (int off = 32; off; off >>= 1) {
        s += __shfl_down(s, off, 64);
        q += __shfl_down(q, off, 64);
    }
    if (t == 0) {
        const double M = (double)DHW;
        double mean = s / M;
        double var  = (q - s * s / M) / (M - 1.0);
        float stdv  = (float)sqrt(var);
        stats[nc]          = (float)mean;
        stats[NC + nc]     = stdv;
        stats[2 * NC + nc] = 1.0f / (stdv + EPSf);
    }
}

// ---------------- Kernel 2: per-z-slice normalized 2D SAT ----------------
__global__ __launch_bounds__(256) void k_sat2d(const float* __restrict__ x,
                                               const float* __restrict__ stats,
                                               float* __restrict__ sat) {
    __shared__ float tile[H * W];          // 65536 B
    const int slice = blockIdx.x;          // nc*D + z
    const int nc = slice / D;
    const int z  = slice % D;
    const int n  = nc / C;
    const int c  = nc % C;
    const float mean = stats[nc];
    const float inv  = stats[2 * NC + nc];
    const float* src = x + (size_t)slice * HW;

    for (int i = threadIdx.x; i < HW; i += 256) {
        int y = i >> 7, xx = i & 127;
        tile[(y << 7) + (xx ^ (y & 31))] = (src[i] - mean) * inv;
    }
    __syncthreads();
    if (threadIdx.x < H) {      // row scan (x)
        const int y = threadIdx.x;
        const int base = y << 7, sw = y & 31;
        float run = 0.f;
        for (int i = 0; i < W; ++i) {
            int a = base + (i ^ sw);
            run += tile[a];
            tile[a] = run;
        }
    }
    __syncthreads();
    if (threadIdx.x < W) {      // column scan (y)
        const int xx = threadIdx.x;
        float run = 0.f;
        for (int y = 0; y < H; ++y) {
            int a = (y << 7) + (xx ^ (y & 31));
            run += tile[a];
            tile[a] = run;
        }
    }
    __syncthreads();
    float* dst = sat + ((size_t)(n * D + z) * HW) * 4 + c;
    for (int i = threadIdx.x; i < HW; i += 256) {
        int y = i >> 7, xx = i & 127;
        dst[(size_t)i * 4] = tile[(y << 7) + (xx ^ (y & 31))];
    }
}

// ---------------- Kernel 3: z-cumsum on interleaved SAT ----------------
// thread-per-f4-column, 32768 threads (was 8192) for occupancy.
__global__ __launch_bounds__(256) void k_satz(float4* __restrict__ sat) {
    const int col = blockIdx.x * 256 + (int)threadIdx.x;   // 0..32767
    const int n   = col >> 14;
    const int rem = col & 16383;        // y*W + x  (float4 coords)
    float4* p = sat + (size_t)n * DHW + rem;
    float4 run = {0, 0, 0, 0};
    #pragma unroll 4
    for (int zz = 0; zz < D; ++zz) {
        float4 a = p[(size_t)zz * HW];
        run.x += a.x; run.y += a.y; run.z += a.z; run.w += a.w;
        p[(size_t)zz * HW] = run;
    }
}

// ---------------- Kernel 4: LDS-staged thread-per-voxel box sample ----------------
__device__ __forceinline__ void taps4(float g, float K, float scale, int lastI,
                                      int* idx, float* wt) {
    float c  = g - K;
    float ix = fminf(fmaxf((c + 1.0f) * scale, 0.0f), (float)lastI);
    float fl = floorf(ix);
    int   i0 = (int)fl;
    float f  = ix - fl;
    idx[0] = i0; idx[1] = min(i0 + 1, lastI);
    wt[0] = -(1.0f - f); wt[1] = -f;
    c  = g + K;
    ix = fminf(fmaxf((c + 1.0f) * scale, 0.0f), (float)lastI);
    fl = floorf(ix);
    i0 = (int)fl;
    f  = ix - fl;
    idx[2] = i0; idx[3] = min(i0 + 1, lastI);
    wt[2] = 1.0f - f; wt[3] = f;
}

__global__ __launch_bounds__(1024) void k_sample(const float4* __restrict__ sat,
                                                 const float* __restrict__ ks,
                                                 const float* __restrict__ stats,
                                                 float* __restrict__ out) {
    extern __shared__ float4 tile[];       // 130048 B dynamic
    // 2048 blocks -> XCD-contiguous swizzle (256 per XCD)
    const int bid = (blockIdx.x & 7) * 256 + (blockIdx.x >> 3);
    const int tx = bid & 7, ty = (bid >> 3) & 7, tz = (bid >> 6) & 15;
    const int n  = bid >> 10;
    const int x0 = tx * TX, y0 = ty * TY, z0 = tz * TZ;
    const int rx0 = x0 - 5, ry0 = y0 - 5, rz0 = z0 - 5;

    const int lane = threadIdx.x & 63;
    const int wid  = threadIdx.x >> 6;     // 0..15
    const float4* satn = sat + (size_t)n * DHW;

    // ---- stage region into LDS: per-lane global src, linear LDS dest ----
    for (int chunk = wid; chunk < RCHUNKS; chunk += 16) {
        int idx  = chunk * 64 + lane;
        int cidx = min(idx, RSLOTS - 1);
        int rz  = cidx / RXY;
        int rem = cidx - rz * RXY;
        int ry  = rem / RX;
        int rx  = rem - ry * RX;
        int gz = min(max(rz0 + rz, 0), D - 1);
        int gy = min(max(ry0 + ry, 0), H - 1);
        int gx = min(max(rx0 + rx, 0), W - 1);
        const float4* src = satn + ((size_t)gz * HW + (size_t)gy * W + gx);
        __builtin_amdgcn_global_load_lds((glb_void*)src,
                                         (lds_void*)&tile[chunk * 64], 16, 0, 0);
    }
    __syncthreads();

    // ---- one voxel per thread ----
    const int v = (int)threadIdx.x;
    const int x = x0 + (v & 15);
    const int y = y0 + ((v >> 4) & 15);
    const int z = z0 + (v >> 8);

    const float* kp = ks + (size_t)(((n * D + z) * H + y) * W + x) * 3;
    const float k0 = kp[0], k1 = kp[1], k2 = kp[2];

    const float gx = -1.0f + (float)x * (2.0f / 127.0f) - (1.0f / 128.0f);
    const float gy = -1.0f + (float)y * (2.0f / 127.0f) - (1.0f / 128.0f);
    const float gz = -1.0f + (float)z * (2.0f / 63.0f)  - (1.0f / 64.0f);

    int xi[4], yi[4], zi[4];
    float wx[4], wy[4], wz[4];
    taps4(gx, k0 * (1.0f / 128.0f), 63.5f, 127, xi, wx);
    taps4(gy, k1 * (1.0f / 128.0f), 63.5f, 127, yi, wy);
    taps4(gz, k2 * (1.0f / 64.0f),  31.5f,  63, zi, wz);

    const int jx0 = xi[0] - rx0, jx1 = xi[1] - rx0;
    const int jx2 = xi[2] - rx0, jx3 = xi[3] - rx0;

    float4 acc = {0, 0, 0, 0};
    #pragma unroll
    for (int vv = 0; vv < 4; ++vv) {
        const int   zb  = (zi[vv] - rz0) * RXY;
        const float wzv = wz[vv];
        #pragma unroll
        for (int u = 0; u < 4; ++u) {
            const int rb = zb + (yi[u] - ry0) * RX;
            float4 s = {0, 0, 0, 0};
            fma4(s, wx[0], tile[rb + jx0]);
            fma4(s, wx[1], tile[rb + jx1]);
            fma4(s, wx[2], tile[rb + jx2]);
            fma4(s, wx[3], tile[rb + jx3]);
            fma4(acc, wzv * wy[u], s);
        }
    }

    const float inva = 1.0f / (k0 * k1 * k2 + EPSf);
    const int sb = n * C;
    float* po = out + (size_t)sb * DHW + (size_t)z * HW + y * W + x;
    po[0]             = acc.x * inva * stats[NC + sb + 0] + stats[sb + 0];
    po[DHW]           = acc.y * inva * stats[NC + sb + 1] + stats[sb + 1];
    po[2 * (size_t)DHW] = acc.z * inva * stats[NC + sb + 2] + stats[sb + 2];
    po[3 * (size_t)DHW] = acc.w * inva * stats[NC + sb + 3] + stats[sb + 3];
}

extern "C" void kernel_launch(void* const* d_in, const int* in_sizes, int n_in,
                              void* d_out, int out_size, void* d_ws, size_t ws_size,
                              hipStream_t stream) {
    const float* x  = (const float*)d_in[0];
    const float* ks = (const float*)d_in[1];
    float* out = (float*)d_out;
    float* ws  = (float*)d_ws;

    float* sat   = ws;                               // NC*DHW floats (interleaved)
    float* psum  = ws + (size_t)NC * DHW;
    float* psq   = psum + NC * RED_BLOCKS;
    float* stats = psq + NC * RED_BLOCKS;

    // allow >64KB dynamic LDS for k_sample (idempotent, not a stream op)
    (void)hipFuncSetAttribute((const void*)k_sample,
                              hipFuncAttributeMaxDynamicSharedMemorySize,
                              RPAD * 16);

    k_reduce<<<NC * RED_BLOCKS, 256, 0, stream>>>(x, psum, psq);
    k_stats <<<NC, 64, 0, stream>>>(psum, psq, stats);
    k_sat2d <<<NC * D, 256, 0, stream>>>(x, stats, sat);
    k_satz  <<<128, 256, 0, stream>>>((float4*)sat);
    k_sample<<<2048, 1024, RPAD * 16, stream>>>((const float4*)sat, ks, stats, out);
}

// Round 6
// 109.906 us; speedup vs baseline: 5.3622x; 1.1491x over previous
//
#include <hip/hip_runtime.h>
#include <math.h>

// Problem shape (fixed by setup_inputs):
//   x:            [N=2, C=4, D=64, H=128, W=128] f32
//   kernel_sizes: [N=2, D=64, H=128, W=128, 3]   f32
//   out:          [N, C, D, H, W] f32
constexpr int N = 2, C = 4, D = 64, H = 128, W = 128;
constexpr int HW  = H * W;        // 16384
constexpr int DHW = D * H * W;    // 1048576
constexpr int NC  = N * C;        // 8
constexpr float EPSf = 1e-5f;

// k_sample tile: 8x8x8 voxels, taps span [c-5, c+4] per dim -> region 17^3
constexpr int RX = 17;
constexpr int RXY = RX * RX;               // 289
constexpr int RSLOTS = RXY * RX;           // 4913
constexpr int RCHUNKS = 77;                // ceil(4913/64)
constexpr int RPAD = RCHUNKS * 64;         // 4928 float4 = 78848 B dynamic LDS

typedef const __attribute__((address_space(1))) void glb_void;
typedef __attribute__((address_space(3))) void lds_void;
typedef __attribute__((ext_vector_type(2))) float f32x2;

// ---------------- Kernel 1: per-z-slice 2D SAT of RAW x + stats partials ----------------
// SAT is built on raw x; normalization is folded into k_sample via the
// separable ones-SAT identity. Per-slice sum/sumsq partials (4 waves each)
// are written non-atomically to pSw/pQw.
__global__ __launch_bounds__(256) void k_sat2d(const float* __restrict__ x,
                                               float* __restrict__ sat,
                                               float* __restrict__ pSw,
                                               float* __restrict__ pQw) {
    __shared__ float tile[H * W];          // 65536 B
    const int slice = blockIdx.x;          // nc*D + z
    const int nc = slice >> 6;
    const int z  = slice & 63;
    const int n  = nc >> 2;
    const int c  = nc & 3;
    const float* src = x + (size_t)slice * HW;

    float s = 0.f, q = 0.f;
    for (int i = threadIdx.x; i < HW; i += 256) {
        int y = i >> 7, xx = i & 127;
        float v = src[i];
        s += v; q += v * v;
        tile[(y << 7) + (xx ^ (y & 31))] = v;
    }
    #pragma unroll
    for (int off = 32; off; off >>= 1) {
        s += __shfl_down(s, off, 64);
        q += __shfl_down(q, off, 64);
    }
    if ((threadIdx.x & 63) == 0) {
        const int w = threadIdx.x >> 6;
        pSw[slice * 4 + w] = s;
        pQw[slice * 4 + w] = q;
    }
    __syncthreads();
    if (threadIdx.x < H) {      // row scan (x)
        const int y = threadIdx.x;
        const int base = y << 7, sw = y & 31;
        float run = 0.f;
        for (int i = 0; i < W; ++i) {
            int a = base + (i ^ sw);
            run += tile[a];
            tile[a] = run;
        }
    }
    __syncthreads();
    if (threadIdx.x < W) {      // column scan (y)
        const int xx = threadIdx.x;
        float run = 0.f;
        for (int y = 0; y < H; ++y) {
            int a = (y << 7) + (xx ^ (y & 31));
            run += tile[a];
            tile[a] = run;
        }
    }
    __syncthreads();
    float* dst = sat + ((size_t)(n * D + z) * HW) * 4 + c;
    for (int i = threadIdx.x; i < HW; i += 256) {
        int y = i >> 7, xx = i & 127;
        dst[(size_t)i * 4] = tile[(y << 7) + (xx ^ (y & 31))];
    }
}

// ---------------- Kernel 2: finalize mean / e = std/(std+EPS) ----------------
__global__ __launch_bounds__(64) void k_stats(const float* __restrict__ pSw,
                                              const float* __restrict__ pQw,
                                              float* __restrict__ stats) {
    const int nc = blockIdx.x;
    const int t  = threadIdx.x;            // one of 64 slices of this nc
    const float4 sv = *(const float4*)(pSw + (size_t)(nc * 64 + t) * 4);
    const float4 qv = *(const float4*)(pQw + (size_t)(nc * 64 + t) * 4);
    double s = (double)sv.x + sv.y + sv.z + sv.w;
    double q = (double)qv.x + qv.y + qv.z + qv.w;
    #pragma unroll
    for (int off = 32; off; off >>= 1) {
        s += __shfl_down(s, off, 64);
        q += __shfl_down(q, off, 64);
    }
    if (t == 0) {
        const double M = (double)DHW;
        double mean = s / M;
        double var  = (q - s * s / M) / (M - 1.0);   // torch ddof=1
        float stdv  = (float)sqrt(var);
        stats[nc]     = (float)mean;
        stats[8 + nc] = stdv / (stdv + EPSf);        // e = std/(std+EPS)
    }
}

// ---------------- Kernel 3: z-cumsum on interleaved SAT ----------------
__global__ __launch_bounds__(256) void k_satz(float4* __restrict__ sat) {
    const int col = blockIdx.x * 256 + (int)threadIdx.x;   // 0..32767
    const int n   = col >> 14;
    const int rem = col & 16383;
    float4* p = sat + (size_t)n * DHW + rem;
    float4 run = {0, 0, 0, 0};
    #pragma unroll 4
    for (int zz = 0; zz < D; ++zz) {
        float4 a = p[(size_t)zz * HW];
        run.x += a.x; run.y += a.y; run.z += a.z; run.w += a.w;
        p[(size_t)zz * HW] = run;
    }
}

// ---------------- Kernel 4: LDS-staged thread-per-voxel box sample ----------------
__device__ __forceinline__ void taps4(float g, float K, float scale, int lastI,
                                      int* idx, float* wt) {
    float c  = g - K;
    float ix = fminf(fmaxf((c + 1.0f) * scale, 0.0f), (float)lastI);
    float fl = floorf(ix);
    int   i0 = (int)fl;
    float f  = ix - fl;
    idx[0] = i0; idx[1] = min(i0 + 1, lastI);
    wt[0] = -(1.0f - f); wt[1] = -f;
    c  = g + K;
    ix = fminf(fmaxf((c + 1.0f) * scale, 0.0f), (float)lastI);
    fl = floorf(ix);
    i0 = (int)fl;
    f  = ix - fl;
    idx[2] = i0; idx[3] = min(i0 + 1, lastI);
    wt[2] = 1.0f - f; wt[3] = f;
}

__global__ __launch_bounds__(512) void k_sample(const float4* __restrict__ sat,
                                                const float* __restrict__ ks,
                                                const float* __restrict__ stats,
                                                float* __restrict__ out) {
    extern __shared__ float4 tile[];       // 78848 B dynamic -> 2 blocks/CU
    // 4096 blocks -> XCD-contiguous swizzle (512 per XCD)
    const int bid = (blockIdx.x & 7) * 512 + (blockIdx.x >> 3);
    const int tx = bid & 15, ty = (bid >> 4) & 15, tz = (bid >> 8) & 7;
    const int n  = bid >> 11;
    const int x0 = tx * 8, y0 = ty * 8, z0 = tz * 8;
    const int rx0 = x0 - 5, ry0 = y0 - 5, rz0 = z0 - 5;

    const int lane = threadIdx.x & 63;
    const int wid  = threadIdx.x >> 6;     // 0..7
    const float4* satn = sat + (size_t)n * DHW;

    // ---- stage 17^3 region into LDS: per-lane global src, linear LDS dest ----
    for (int chunk = wid; chunk < RCHUNKS; chunk += 8) {
        int idx  = chunk * 64 + lane;
        int cidx = min(idx, RSLOTS - 1);
        int rz  = cidx / RXY;
        int rem = cidx - rz * RXY;
        int ry  = rem / RX;
        int rx  = rem - ry * RX;
        int gz = min(max(rz0 + rz, 0), D - 1);
        int gy = min(max(ry0 + ry, 0), H - 1);
        int gx = min(max(rx0 + rx, 0), W - 1);
        const float4* src = satn + ((size_t)gz * HW + (size_t)gy * W + gx);
        __builtin_amdgcn_global_load_lds((glb_void*)src,
                                         (lds_void*)&tile[chunk * 64], 16, 0, 0);
    }
    __syncthreads();

    // ---- one voxel per thread ----
    const int v = (int)threadIdx.x;
    const int x = x0 + (v & 7);
    const int y = y0 + ((v >> 3) & 7);
    const int z = z0 + (v >> 6);

    const float* kp = ks + (size_t)(((n * D + z) * H + y) * W + x) * 3;
    const float k0 = kp[0], k1 = kp[1], k2 = kp[2];

    const float gx = -1.0f + (float)x * (2.0f / 127.0f) - (1.0f / 128.0f);
    const float gy = -1.0f + (float)y * (2.0f / 127.0f) - (1.0f / 128.0f);
    const float gz = -1.0f + (float)z * (2.0f / 63.0f)  - (1.0f / 64.0f);

    int xi[4], yi[4], zi[4];
    float wx[4], wy[4], wz[4];
    taps4(gx, k0 * (1.0f / 128.0f), 63.5f, 127, xi, wx);
    taps4(gy, k1 * (1.0f / 128.0f), 63.5f, 127, yi, wy);
    taps4(gz, k2 * (1.0f / 64.0f),  31.5f,  63, zi, wz);

    // separable count factors (taps applied to the ones-SAT (i+1)(j+1)(k+1))
    const float cx = wx[0] * (float)(xi[0] + 1) + wx[1] * (float)(xi[1] + 1)
                   + wx[2] * (float)(xi[2] + 1) + wx[3] * (float)(xi[3] + 1);
    const float cy = wy[0] * (float)(yi[0] + 1) + wy[1] * (float)(yi[1] + 1)
                   + wy[2] * (float)(yi[2] + 1) + wy[3] * (float)(yi[3] + 1);
    const float cz = wz[0] * (float)(zi[0] + 1) + wz[1] * (float)(zi[1] + 1)
                   + wz[2] * (float)(zi[2] + 1) + wz[3] * (float)(zi[3] + 1);
    const float cnt = cx * cy * cz;

    const int jx0 = xi[0] - rx0, jx1 = xi[1] - rx0;
    const int jx2 = xi[2] - rx0, jx3 = xi[3] - rx0;
    const f32x2 w0 = {wx[0], wx[0]}, w1 = {wx[1], wx[1]};
    const f32x2 w2 = {wx[2], wx[2]}, w3 = {wx[3], wx[3]};

    f32x2 aL = {0, 0}, aH = {0, 0};        // channels {0,1}, {2,3}
    #pragma unroll
    for (int vv = 0; vv < 4; ++vv) {
        const int   zb  = (zi[vv] - rz0) * RXY;
        const float wzv = wz[vv];
        #pragma unroll
        for (int u = 0; u < 4; ++u) {
            const int rb = zb + (yi[u] - ry0) * RX;
            float4 t0 = tile[rb + jx0];
            float4 t1 = tile[rb + jx1];
            float4 t2 = tile[rb + jx2];
            float4 t3 = tile[rb + jx3];
            f32x2 sL = w0 * f32x2{t0.x, t0.y} + w1 * f32x2{t1.x, t1.y}
                     + w2 * f32x2{t2.x, t2.y} + w3 * f32x2{t3.x, t3.y};
            f32x2 sH = w0 * f32x2{t0.z, t0.w} + w1 * f32x2{t1.z, t1.w}
                     + w2 * f32x2{t2.z, t2.w} + w3 * f32x2{t3.z, t3.w};
            const float wvu = wzv * wy[u];
            const f32x2 ww = {wvu, wvu};
            aL += ww * sL;
            aH += ww * sH;
        }
    }

    // out_c = (T_c - mean_c*cnt) * e_c * inva + mean_c
    const float inva = 1.0f / (k0 * k1 * k2 + EPSf);
    const float4 m4 = *(const float4*)(stats + n * 4);
    const float4 e4 = *(const float4*)(stats + 8 + n * 4);
    const int sb = n * C;
    float* po = out + (size_t)sb * DHW + (size_t)z * HW + y * W + x;
    po[0]               = (aL.x - m4.x * cnt) * (e4.x * inva) + m4.x;
    po[DHW]             = (aL.y - m4.y * cnt) * (e4.y * inva) + m4.y;
    po[2 * (size_t)DHW] = (aH.x - m4.z * cnt) * (e4.z * inva) + m4.z;
    po[3 * (size_t)DHW] = (aH.y - m4.w * cnt) * (e4.w * inva) + m4.w;
}

extern "C" void kernel_launch(void* const* d_in, const int* in_sizes, int n_in,
                              void* d_out, int out_size, void* d_ws, size_t ws_size,
                              hipStream_t stream) {
    const float* x  = (const float*)d_in[0];
    const float* ks = (const float*)d_in[1];
    float* out = (float*)d_out;
    float* ws  = (float*)d_ws;

    float* sat   = ws;                               // NC*DHW floats (interleaved)
    float* pSw   = ws + (size_t)NC * DHW;            // 512*4
    float* pQw   = pSw + 2048;                       // 512*4
    float* stats = pQw + 2048;                       // 16 floats: mean[8], e[8]

    (void)hipFuncSetAttribute((const void*)k_sample,
                              hipFuncAttributeMaxDynamicSharedMemorySize,
                              RPAD * 16);

    k_sat2d <<<NC * D, 256, 0, stream>>>(x, sat, pSw, pQw);
    k_stats <<<NC, 64, 0, stream>>>(pSw, pQw, stats);
    k_satz  <<<128, 256, 0, stream>>>((float4*)sat);
    k_sample<<<4096, 512, RPAD * 16, stream>>>((const float4*)sat, ks, stats, out);
}

// Round 7
// 106.702 us; speedup vs baseline: 5.5232x; 1.0300x over previous
//
#include <hip/hip_runtime.h>
#include <math.h>

// Problem shape (fixed by setup_inputs):
//   x:            [N=2, C=4, D=64, H=128, W=128] f32
//   kernel_sizes: [N=2, D=64, H=128, W=128, 3]   f32
//   out:          [N, C, D, H, W] f32
constexpr int N = 2, C = 4, D = 64, H = 128, W = 128;
constexpr int HW  = H * W;        // 16384
constexpr int DHW = D * H * W;    // 1048576
constexpr int NC  = N * C;        // 8
constexpr float EPSf = 1e-5f;

// k_sample tile: 8x8x8 voxels, taps span [c-5, c+4] per dim -> region 17^3
constexpr int RX = 17;
constexpr int RXY = RX * RX;               // 289
constexpr int RSLOTS = RXY * RX;           // 4913
constexpr int RCHUNKS = 77;                // ceil(4913/64)
constexpr int RPAD = RCHUNKS * 64;         // 4928 float4 = 78848 B dynamic LDS

typedef const __attribute__((address_space(1))) void glb_void;
typedef __attribute__((address_space(3))) void lds_void;
typedef __attribute__((ext_vector_type(2))) float f32x2;

// ---------------- Kernel 1: per-z-slice 2D SAT of RAW x + stats partials ----------------
// Output is the 2D (x,y)-SAT per slice, channel-interleaved. NO z-cumsum:
// k_sample derives local z-prefixes in LDS (z-tap weights sum to 0, so any
// constant z-offset cancels). Column scan is fused with the global write.
__global__ __launch_bounds__(256) void k_sat2d(const float* __restrict__ x,
                                               float* __restrict__ sat,
                                               float* __restrict__ pSw,
                                               float* __restrict__ pQw) {
    __shared__ float tile[H * W];          // 65536 B
    const int slice = blockIdx.x;          // nc*D + z
    const int nc = slice >> 6;
    const int z  = slice & 63;
    const int n  = nc >> 2;
    const int c  = nc & 3;
    const float* src = x + (size_t)slice * HW;

    float s = 0.f, q = 0.f;
    for (int i = threadIdx.x; i < HW; i += 256) {
        int y = i >> 7, xx = i & 127;
        float v = src[i];
        s += v; q += v * v;
        tile[(y << 7) + (xx ^ (y & 31))] = v;
    }
    #pragma unroll
    for (int off = 32; off; off >>= 1) {
        s += __shfl_down(s, off, 64);
        q += __shfl_down(q, off, 64);
    }
    if ((threadIdx.x & 63) == 0) {
        const int w = threadIdx.x >> 6;
        pSw[slice * 4 + w] = s;
        pQw[slice * 4 + w] = q;
    }
    __syncthreads();
    if (threadIdx.x < H) {      // row scan (x)
        const int y = threadIdx.x;
        const int base = y << 7, sw = y & 31;
        float run = 0.f;
        for (int i = 0; i < W; ++i) {
            int a = base + (i ^ sw);
            run += tile[a];
            tile[a] = run;
        }
    }
    __syncthreads();
    // column scan (y) fused with interleaved global write
    if (threadIdx.x < W) {
        const int xx = threadIdx.x;
        float* dst = sat + ((size_t)(n * D + z) * HW) * 4 + c;
        float run = 0.f;
        for (int y = 0; y < H; ++y) {
            run += tile[(y << 7) + (xx ^ (y & 31))];
            dst[(size_t)(y * W + xx) * 4] = run;
        }
    }
}

// ---------------- Kernel 2: finalize mean / e = std/(std+EPS) ----------------
__global__ __launch_bounds__(64) void k_stats(const float* __restrict__ pSw,
                                              const float* __restrict__ pQw,
                                              float* __restrict__ stats) {
    const int nc = blockIdx.x;
    const int t  = threadIdx.x;            // one of 64 slices of this nc
    const float4 sv = *(const float4*)(pSw + (size_t)(nc * 64 + t) * 4);
    const float4 qv = *(const float4*)(pQw + (size_t)(nc * 64 + t) * 4);
    double s = (double)sv.x + sv.y + sv.z + sv.w;
    double q = (double)qv.x + qv.y + qv.z + qv.w;
    #pragma unroll
    for (int off = 32; off; off >>= 1) {
        s += __shfl_down(s, off, 64);
        q += __shfl_down(q, off, 64);
    }
    if (t == 0) {
        const double M = (double)DHW;
        double mean = s / M;
        double var  = (q - s * s / M) / (M - 1.0);   // torch ddof=1
        float stdv  = (float)sqrt(var);
        stats[nc]     = (float)mean;
        stats[8 + nc] = stdv / (stdv + EPSf);        // e = std/(std+EPS)
    }
}

// ---------------- Kernel 3: LDS-staged thread-per-voxel box sample ----------------
__device__ __forceinline__ void taps4(float g, float K, float scale, int lastI,
                                      int* idx, float* wt) {
    float c  = g - K;
    float ix = fminf(fmaxf((c + 1.0f) * scale, 0.0f), (float)lastI);
    float fl = floorf(ix);
    int   i0 = (int)fl;
    float f  = ix - fl;
    idx[0] = i0; idx[1] = min(i0 + 1, lastI);
    wt[0] = -(1.0f - f); wt[1] = -f;
    c  = g + K;
    ix = fminf(fmaxf((c + 1.0f) * scale, 0.0f), (float)lastI);
    fl = floorf(ix);
    i0 = (int)fl;
    f  = ix - fl;
    idx[2] = i0; idx[3] = min(i0 + 1, lastI);
    wt[2] = 1.0f - f; wt[3] = f;
}

__global__ __launch_bounds__(512) void k_sample(const float4* __restrict__ sat,
                                                const float* __restrict__ ks,
                                                const float* __restrict__ stats,
                                                float* __restrict__ out) {
    extern __shared__ float4 tile[];       // 78848 B dynamic -> 2 blocks/CU
    // 4096 blocks -> XCD-contiguous swizzle (512 per XCD)
    const int bid = (blockIdx.x & 7) * 512 + (blockIdx.x >> 3);
    const int tx = bid & 15, ty = (bid >> 4) & 15, tz = (bid >> 8) & 7;
    const int n  = bid >> 11;
    const int x0 = tx * 8, y0 = ty * 8, z0 = tz * 8;
    const int rx0 = x0 - 5, ry0 = y0 - 5, rz0 = z0 - 5;

    const int lane = threadIdx.x & 63;
    const int wid  = threadIdx.x >> 6;     // 0..7
    const float4* satn = sat + (size_t)n * DHW;

    // ---- stage 17^3 region of 2D-SAT slices: per-lane global src, linear LDS dest ----
    for (int chunk = wid; chunk < RCHUNKS; chunk += 8) {
        int idx  = chunk * 64 + lane;
        int cidx = min(idx, RSLOTS - 1);
        int rz  = cidx / RXY;
        int rem = cidx - rz * RXY;
        int ry  = rem / RX;
        int rx  = rem - ry * RX;
        int gz = min(max(rz0 + rz, 0), D - 1);
        int gy = min(max(ry0 + ry, 0), H - 1);
        int gx = min(max(rx0 + rx, 0), W - 1);
        const float4* src = satn + ((size_t)gz * HW + (size_t)gy * W + gx);
        __builtin_amdgcn_global_load_lds((glb_void*)src,
                                         (lds_void*)&tile[chunk * 64], 16, 0, 0);
    }
    __syncthreads();

    // ---- local z-prefix over the 17 staged slices (per xy-column) ----
    // Border-clamp duplicate slices add a constant offset to every prefix
    // entry a voxel's taps can touch; z-tap weights sum to 0 -> cancels.
    for (int col = threadIdx.x; col < RXY; col += 512) {
        float4 run = tile[col];
        #pragma unroll
        for (int j = 1; j < RX; ++j) {
            float4 a = tile[j * RXY + col];
            run.x += a.x; run.y += a.y; run.z += a.z; run.w += a.w;
            tile[j * RXY + col] = run;
        }
    }
    __syncthreads();

    // ---- one voxel per thread ----
    const int v = (int)threadIdx.x;
    const int x = x0 + (v & 7);
    const int y = y0 + ((v >> 3) & 7);
    const int z = z0 + (v >> 6);

    const float* kp = ks + (size_t)(((n * D + z) * H + y) * W + x) * 3;
    const float k0 = kp[0], k1 = kp[1], k2 = kp[2];

    const float gx = -1.0f + (float)x * (2.0f / 127.0f) - (1.0f / 128.0f);
    const float gy = -1.0f + (float)y * (2.0f / 127.0f) - (1.0f / 128.0f);
    const float gz = -1.0f + (float)z * (2.0f / 63.0f)  - (1.0f / 64.0f);

    int xi[4], yi[4], zi[4];
    float wx[4], wy[4], wz[4];
    taps4(gx, k0 * (1.0f / 128.0f), 63.5f, 127, xi, wx);
    taps4(gy, k1 * (1.0f / 128.0f), 63.5f, 127, yi, wy);
    taps4(gz, k2 * (1.0f / 64.0f),  31.5f,  63, zi, wz);

    // separable count factors (taps applied to the ones-SAT (i+1)(j+1)(k+1))
    const float cx = wx[0] * (float)(xi[0] + 1) + wx[1] * (float)(xi[1] + 1)
                   + wx[2] * (float)(xi[2] + 1) + wx[3] * (float)(xi[3] + 1);
    const float cy = wy[0] * (float)(yi[0] + 1) + wy[1] * (float)(yi[1] + 1)
                   + wy[2] * (float)(yi[2] + 1) + wy[3] * (float)(yi[3] + 1);
    const float cz = wz[0] * (float)(zi[0] + 1) + wz[1] * (float)(zi[1] + 1)
                   + wz[2] * (float)(zi[2] + 1) + wz[3] * (float)(zi[3] + 1);
    const float cnt = cx * cy * cz;

    const int jx0 = xi[0] - rx0, jx1 = xi[1] - rx0;
    const int jx2 = xi[2] - rx0, jx3 = xi[3] - rx0;
    const f32x2 w0 = {wx[0], wx[0]}, w1 = {wx[1], wx[1]};
    const f32x2 w2 = {wx[2], wx[2]}, w3 = {wx[3], wx[3]};

    f32x2 aL = {0, 0}, aH = {0, 0};        // channels {0,1}, {2,3}
    #pragma unroll
    for (int vv = 0; vv < 4; ++vv) {
        const int   zb  = (zi[vv] - rz0) * RXY;
        const float wzv = wz[vv];
        #pragma unroll
        for (int u = 0; u < 4; ++u) {
            const int rb = zb + (yi[u] - ry0) * RX;
            float4 t0 = tile[rb + jx0];
            float4 t1 = tile[rb + jx1];
            float4 t2 = tile[rb + jx2];
            float4 t3 = tile[rb + jx3];
            f32x2 sL = w0 * f32x2{t0.x, t0.y} + w1 * f32x2{t1.x, t1.y}
                     + w2 * f32x2{t2.x, t2.y} + w3 * f32x2{t3.x, t3.y};
            f32x2 sH = w0 * f32x2{t0.z, t0.w} + w1 * f32x2{t1.z, t1.w}
                     + w2 * f32x2{t2.z, t2.w} + w3 * f32x2{t3.z, t3.w};
            const float wvu = wzv * wy[u];
            const f32x2 ww = {wvu, wvu};
            aL += ww * sL;
            aH += ww * sH;
        }
    }

    // out_c = (T_c - mean_c*cnt) * e_c * inva + mean_c
    const float inva = 1.0f / (k0 * k1 * k2 + EPSf);
    const float4 m4 = *(const float4*)(stats + n * 4);
    const float4 e4 = *(const float4*)(stats + 8 + n * 4);
    const int sb = n * C;
    float* po = out + (size_t)sb * DHW + (size_t)z * HW + y * W + x;
    po[0]               = (aL.x - m4.x * cnt) * (e4.x * inva) + m4.x;
    po[DHW]             = (aL.y - m4.y * cnt) * (e4.y * inva) + m4.y;
    po[2 * (size_t)DHW] = (aH.x - m4.z * cnt) * (e4.z * inva) + m4.z;
    po[3 * (size_t)DHW] = (aH.y - m4.w * cnt) * (e4.w * inva) + m4.w;
}

extern "C" void kernel_launch(void* const* d_in, const int* in_sizes, int n_in,
                              void* d_out, int out_size, void* d_ws, size_t ws_size,
                              hipStream_t stream) {
    const float* x  = (const float*)d_in[0];
    const float* ks = (const float*)d_in[1];
    float* out = (float*)d_out;
    float* ws  = (float*)d_ws;

    float* sat   = ws;                               // NC*DHW floats (interleaved 2D-SAT)
    float* pSw   = ws + (size_t)NC * DHW;            // 512*4
    float* pQw   = pSw + 2048;                       // 512*4
    float* stats = pQw + 2048;                       // 16 floats: mean[8], e[8]

    (void)hipFuncSetAttribute((const void*)k_sample,
                              hipFuncAttributeMaxDynamicSharedMemorySize,
                              RPAD * 16);

    k_sat2d <<<NC * D, 256, 0, stream>>>(x, sat, pSw, pQw);
    k_stats <<<NC, 64, 0, stream>>>(pSw, pQw, stats);
    k_sample<<<4096, 512, RPAD * 16, stream>>>((const float4*)sat, ks, stats, out);
}

// Round 8
// 102.798 us; speedup vs baseline: 5.7329x; 1.0380x over previous
//
#include <hip/hip_runtime.h>
#include <math.h>

// Problem shape (fixed by setup_inputs):
//   x:            [N=2, C=4, D=64, H=128, W=128] f32
//   kernel_sizes: [N=2, D=64, H=128, W=128, 3]   f32
//   out:          [N, C, D, H, W] f32
constexpr int N = 2, C = 4, D = 64, H = 128, W = 128;
constexpr int HW  = H * W;        // 16384
constexpr int DHW = D * H * W;    // 1048576
constexpr int NC  = N * C;        // 8
constexpr float EPSf = 1e-5f;

// k_sample tile: 8x8x8 voxels, taps span [c-5, c+4] per dim -> region 17^3
constexpr int RX = 17;
constexpr int RXY = RX * RX;               // 289
constexpr int RSLOTS = RXY * RX;           // 4913 float4 = 78608 B dynamic LDS

typedef __attribute__((ext_vector_type(2))) float f32x2;

// ---------------- Kernel 1: per-z-slice 2D SAT of RAW x + stats partials ----------------
// Output is the 2D (x,y)-SAT per slice, channel-interleaved. NO z-cumsum:
// k_sample builds local z-prefixes in registers during staging (z-tap weights
// sum to 0, so the constant offset from clamp-duplicated slices cancels).
__global__ __launch_bounds__(256) void k_sat2d(const float* __restrict__ x,
                                               float* __restrict__ sat,
                                               float* __restrict__ pSw,
                                               float* __restrict__ pQw) {
    __shared__ float tile[H * W];          // 65536 B
    const int slice = blockIdx.x;          // nc*D + z
    const int nc = slice >> 6;
    const int z  = slice & 63;
    const int n  = nc >> 2;
    const int c  = nc & 3;
    const float* src = x + (size_t)slice * HW;

    float s = 0.f, q = 0.f;
    for (int i = threadIdx.x; i < HW; i += 256) {
        int y = i >> 7, xx = i & 127;
        float v = src[i];
        s += v; q += v * v;
        tile[(y << 7) + (xx ^ (y & 31))] = v;
    }
    #pragma unroll
    for (int off = 32; off; off >>= 1) {
        s += __shfl_down(s, off, 64);
        q += __shfl_down(q, off, 64);
    }
    if ((threadIdx.x & 63) == 0) {
        const int w = threadIdx.x >> 6;
        pSw[slice * 4 + w] = s;
        pQw[slice * 4 + w] = q;
    }
    __syncthreads();
    if (threadIdx.x < H) {      // row scan (x)
        const int y = threadIdx.x;
        const int base = y << 7, sw = y & 31;
        float run = 0.f;
        for (int i = 0; i < W; ++i) {
            int a = base + (i ^ sw);
            run += tile[a];
            tile[a] = run;
        }
    }
    __syncthreads();
    // column scan (y) fused with interleaved global write
    if (threadIdx.x < W) {
        const int xx = threadIdx.x;
        float* dst = sat + ((size_t)(n * D + z) * HW) * 4 + c;
        float run = 0.f;
        for (int y = 0; y < H; ++y) {
            run += tile[(y << 7) + (xx ^ (y & 31))];
            dst[(size_t)(y * W + xx) * 4] = run;
        }
    }
}

// ---------------- Kernel 2: finalize mean / e = std/(std+EPS) ----------------
__global__ __launch_bounds__(64) void k_stats(const float* __restrict__ pSw,
                                              const float* __restrict__ pQw,
                                              float* __restrict__ stats) {
    const int nc = blockIdx.x;
    const int t  = threadIdx.x;            // one of 64 slices of this nc
    const float4 sv = *(const float4*)(pSw + (size_t)(nc * 64 + t) * 4);
    const float4 qv = *(const float4*)(pQw + (size_t)(nc * 64 + t) * 4);
    double s = (double)sv.x + sv.y + sv.z + sv.w;
    double q = (double)qv.x + qv.y + qv.z + qv.w;
    #pragma unroll
    for (int off = 32; off; off >>= 1) {
        s += __shfl_down(s, off, 64);
        q += __shfl_down(q, off, 64);
    }
    if (t == 0) {
        const double M = (double)DHW;
        double mean = s / M;
        double var  = (q - s * s / M) / (M - 1.0);   // torch ddof=1
        float stdv  = (float)sqrt(var);
        stats[nc]     = (float)mean;
        stats[8 + nc] = stdv / (stdv + EPSf);        // e = std/(std+EPS)
    }
}

// ---------------- Kernel 3: LDS-staged thread-per-voxel box sample ----------------
__device__ __forceinline__ void taps4(float g, float K, float scale, int lastI,
                                      int* idx, float* wt) {
    float c  = g - K;
    float ix = fminf(fmaxf((c + 1.0f) * scale, 0.0f), (float)lastI);
    float fl = floorf(ix);
    int   i0 = (int)fl;
    float f  = ix - fl;
    idx[0] = i0; idx[1] = min(i0 + 1, lastI);
    wt[0] = -(1.0f - f); wt[1] = -f;
    c  = g + K;
    ix = fminf(fmaxf((c + 1.0f) * scale, 0.0f), (float)lastI);
    fl = floorf(ix);
    i0 = (int)fl;
    f  = ix - fl;
    idx[2] = i0; idx[3] = min(i0 + 1, lastI);
    wt[2] = 1.0f - f; wt[3] = f;
}

__global__ __launch_bounds__(512, 4) void k_sample(const float4* __restrict__ sat,
                                                   const float* __restrict__ ks,
                                                   const float* __restrict__ stats,
                                                   float* __restrict__ out) {
    extern __shared__ float4 tile[];       // 78608 B dynamic -> 2 blocks/CU
    // 4096 blocks -> XCD-contiguous swizzle (512 per XCD)
    const int bid = (blockIdx.x & 7) * 512 + (blockIdx.x >> 3);
    const int tx = bid & 15, ty = (bid >> 4) & 15, tz = (bid >> 8) & 7;
    const int n  = bid >> 11;
    const int x0 = tx * 8, y0 = ty * 8, z0 = tz * 8;
    const int rx0 = x0 - 5, ry0 = y0 - 5, rz0 = z0 - 5;

    const float4* satn = sat + (size_t)n * DHW;

    // ---- voxel coords + ks load issued first (latency overlap) ----
    const int v = (int)threadIdx.x;
    const int x = x0 + (v & 7);
    const int y = y0 + ((v >> 3) & 7);
    const int z = z0 + (v >> 6);
    const float* kp = ks + (size_t)(((n * D + z) * H + y) * W + x) * 3;
    const float k0 = kp[0], k1 = kp[1], k2 = kp[2];

    // ---- stage: one (x,y) column per thread; z-prefix accumulated in VGPR ----
    // (removes the in-LDS prefix pass: LDS pipe only sees the 4913 ds_writes)
    for (int col = threadIdx.x; col < RXY; col += 512) {
        const int ry = col / RX, rx = col - ry * RX;
        const int gy = min(max(ry0 + ry, 0), H - 1);
        const int gx = min(max(rx0 + rx, 0), W - 1);
        const float4* srcp = satn + ((size_t)gy * W + gx);
        float4 run = {0, 0, 0, 0};
        #pragma unroll
        for (int j = 0; j < RX; ++j) {
            const int gz = min(max(rz0 + j, 0), D - 1);
            float4 a = srcp[(size_t)gz * HW];
            run.x += a.x; run.y += a.y; run.z += a.z; run.w += a.w;
            tile[j * RXY + col] = run;
        }
    }

    // ---- tap math (pure VALU) before the barrier: overlaps staging drain ----
    const float gx = -1.0f + (float)x * (2.0f / 127.0f) - (1.0f / 128.0f);
    const float gy = -1.0f + (float)y * (2.0f / 127.0f) - (1.0f / 128.0f);
    const float gz = -1.0f + (float)z * (2.0f / 63.0f)  - (1.0f / 64.0f);

    int xi[4], yi[4], zi[4];
    float wx[4], wy[4], wz[4];
    taps4(gx, k0 * (1.0f / 128.0f), 63.5f, 127, xi, wx);
    taps4(gy, k1 * (1.0f / 128.0f), 63.5f, 127, yi, wy);
    taps4(gz, k2 * (1.0f / 64.0f),  31.5f,  63, zi, wz);

    // separable count factors (taps applied to the ones-SAT (i+1)(j+1)(k+1))
    const float cx = wx[0] * (float)(xi[0] + 1) + wx[1] * (float)(xi[1] + 1)
                   + wx[2] * (float)(xi[2] + 1) + wx[3] * (float)(xi[3] + 1);
    const float cy = wy[0] * (float)(yi[0] + 1) + wy[1] * (float)(yi[1] + 1)
                   + wy[2] * (float)(yi[2] + 1) + wy[3] * (float)(yi[3] + 1);
    const float cz = wz[0] * (float)(zi[0] + 1) + wz[1] * (float)(zi[1] + 1)
                   + wz[2] * (float)(zi[2] + 1) + wz[3] * (float)(zi[3] + 1);
    const float cnt = cx * cy * cz;

    const int jx0 = xi[0] - rx0, jx1 = xi[1] - rx0;
    const int jx2 = xi[2] - rx0, jx3 = xi[3] - rx0;
    const f32x2 w0 = {wx[0], wx[0]}, w1 = {wx[1], wx[1]};
    const f32x2 w2 = {wx[2], wx[2]}, w3 = {wx[3], wx[3]};

    __syncthreads();

    f32x2 aL = {0, 0}, aH = {0, 0};        // channels {0,1}, {2,3}
    #pragma unroll
    for (int vv = 0; vv < 4; ++vv) {
        const int   zb  = (zi[vv] - rz0) * RXY;
        const float wzv = wz[vv];
        #pragma unroll
        for (int u = 0; u < 4; ++u) {
            const int rb = zb + (yi[u] - ry0) * RX;
            float4 t0 = tile[rb + jx0];
            float4 t1 = tile[rb + jx1];
            float4 t2 = tile[rb + jx2];
            float4 t3 = tile[rb + jx3];
            f32x2 sL = w0 * f32x2{t0.x, t0.y} + w1 * f32x2{t1.x, t1.y}
                     + w2 * f32x2{t2.x, t2.y} + w3 * f32x2{t3.x, t3.y};
            f32x2 sH = w0 * f32x2{t0.z, t0.w} + w1 * f32x2{t1.z, t1.w}
                     + w2 * f32x2{t2.z, t2.w} + w3 * f32x2{t3.z, t3.w};
            const float wvu = wzv * wy[u];
            const f32x2 ww = {wvu, wvu};
            aL += ww * sL;
            aH += ww * sH;
        }
    }

    // out_c = (T_c - mean_c*cnt) * e_c * inva + mean_c
    const float inva = 1.0f / (k0 * k1 * k2 + EPSf);
    const float4 m4 = *(const float4*)(stats + n * 4);
    const float4 e4 = *(const float4*)(stats + 8 + n * 4);
    const int sb = n * C;
    float* po = out + (size_t)sb * DHW + (size_t)z * HW + y * W + x;
    po[0]               = (aL.x - m4.x * cnt) * (e4.x * inva) + m4.x;
    po[DHW]             = (aL.y - m4.y * cnt) * (e4.y * inva) + m4.y;
    po[2 * (size_t)DHW] = (aH.x - m4.z * cnt) * (e4.z * inva) + m4.z;
    po[3 * (size_t)DHW] = (aH.y - m4.w * cnt) * (e4.w * inva) + m4.w;
}

extern "C" void kernel_launch(void* const* d_in, const int* in_sizes, int n_in,
                              void* d_out, int out_size, void* d_ws, size_t ws_size,
                              hipStream_t stream) {
    const float* x  = (const float*)d_in[0];
    const float* ks = (const float*)d_in[1];
    float* out = (float*)d_out;
    float* ws  = (float*)d_ws;

    float* sat   = ws;                               // NC*DHW floats (interleaved 2D-SAT)
    float* pSw   = ws + (size_t)NC * DHW;            // 512*4
    float* pQw   = pSw + 2048;                       // 512*4
    float* stats = pQw + 2048;                       // 16 floats: mean[8], e[8]

    (void)hipFuncSetAttribute((const void*)k_sample,
                              hipFuncAttributeMaxDynamicSharedMemorySize,
                              RSLOTS * 16);

    k_sat2d <<<NC * D, 256, 0, stream>>>(x, sat, pSw, pQw);
    k_stats <<<NC, 64, 0, stream>>>(pSw, pQw, stats);
    k_sample<<<4096, 512, RSLOTS * 16, stream>>>((const float4*)sat, ks, stats, out);
}

// Round 9
// 98.980 us; speedup vs baseline: 5.9541x; 1.0386x over previous
//
#include <hip/hip_runtime.h>
#include <math.h>

// Problem shape (fixed by setup_inputs):
//   x:            [N=2, C=4, D=64, H=128, W=128] f32
//   kernel_sizes: [N=2, D=64, H=128, W=128, 3]   f32
//   out:          [N, C, D, H, W] f32
constexpr int N = 2, C = 4, D = 64, H = 128, W = 128;
constexpr int HW  = H * W;        // 16384
constexpr int DHW = D * H * W;    // 1048576
constexpr int NC  = N * C;        // 8
constexpr float EPSf = 1e-5f;

// k_sample tile: 8x8x8 voxels, taps span [c-5, c+4] per dim -> region 17^3
constexpr int RX = 17;
constexpr int RXY = RX * RX;               // 289
constexpr int RSLOTS = RXY * RX;           // 4913 float4 = 78608 B dynamic LDS

typedef __attribute__((ext_vector_type(2))) float f32x2;

// ---------------- Kernel 1: per-z-slice 2D SAT of RAW x + stats partials ----------------
// Output: PLANAR per-channel 2D-SAT, layout [n][z][c][H][W] (coalesced writes).
// NO z-cumsum: k_sample builds local z-prefixes in registers during staging
// (z-tap weights sum to 0, so the clamp-duplicate constant offset cancels).
__global__ __launch_bounds__(256) void k_sat2d(const float* __restrict__ x,
                                               float* __restrict__ sat,
                                               float* __restrict__ pSw,
                                               float* __restrict__ pQw) {
    __shared__ float tile[H * W];          // 65536 B
    const int slice = blockIdx.x;          // nc*D + z
    const int nc = slice >> 6;
    const int z  = slice & 63;
    const int n  = nc >> 2;
    const int c  = nc & 3;
    const float* src = x + (size_t)slice * HW;

    float s = 0.f, q = 0.f;
    for (int i = threadIdx.x; i < HW; i += 256) {
        int y = i >> 7, xx = i & 127;
        float v = src[i];
        s += v; q += v * v;
        tile[(y << 7) + (xx ^ (y & 31))] = v;
    }
    #pragma unroll
    for (int off = 32; off; off >>= 1) {
        s += __shfl_down(s, off, 64);
        q += __shfl_down(q, off, 64);
    }
    if ((threadIdx.x & 63) == 0) {
        const int w = threadIdx.x >> 6;
        pSw[slice * 4 + w] = s;
        pQw[slice * 4 + w] = q;
    }
    __syncthreads();
    if (threadIdx.x < H) {      // row scan (x)
        const int y = threadIdx.x;
        const int base = y << 7, sw = y & 31;
        float run = 0.f;
        for (int i = 0; i < W; ++i) {
            int a = base + (i ^ sw);
            run += tile[a];
            tile[a] = run;
        }
    }
    __syncthreads();
    // column scan (y) fused with PLANAR coalesced global write
    if (threadIdx.x < W) {
        const int xx = threadIdx.x;
        float* dst = sat + ((size_t)(n * D + z) * C + c) * HW + xx;
        float run = 0.f;
        for (int y = 0; y < H; ++y) {
            run += tile[(y << 7) + (xx ^ (y & 31))];
            dst[(size_t)y * W] = run;
        }
    }
}

// ---------------- Kernel 2: finalize mean / e = std/(std+EPS) ----------------
__global__ __launch_bounds__(64) void k_stats(const float* __restrict__ pSw,
                                              const float* __restrict__ pQw,
                                              float* __restrict__ stats) {
    const int nc = blockIdx.x;
    const int t  = threadIdx.x;            // one of 64 slices of this nc
    const float4 sv = *(const float4*)(pSw + (size_t)(nc * 64 + t) * 4);
    const float4 qv = *(const float4*)(pQw + (size_t)(nc * 64 + t) * 4);
    double s = (double)sv.x + sv.y + sv.z + sv.w;
    double q = (double)qv.x + qv.y + qv.z + qv.w;
    #pragma unroll
    for (int off = 32; off; off >>= 1) {
        s += __shfl_down(s, off, 64);
        q += __shfl_down(q, off, 64);
    }
    if (t == 0) {
        const double M = (double)DHW;
        double mean = s / M;
        double var  = (q - s * s / M) / (M - 1.0);   // torch ddof=1
        float stdv  = (float)sqrt(var);
        stats[nc]     = (float)mean;
        stats[8 + nc] = stdv / (stdv + EPSf);        // e = std/(std+EPS)
    }
}

// ---------------- Kernel 3: LDS-staged thread-per-voxel box sample ----------------
__device__ __forceinline__ void taps4(float g, float K, float scale, int lastI,
                                      int* idx, float* wt) {
    float c  = g - K;
    float ix = fminf(fmaxf((c + 1.0f) * scale, 0.0f), (float)lastI);
    float fl = floorf(ix);
    int   i0 = (int)fl;
    float f  = ix - fl;
    idx[0] = i0; idx[1] = min(i0 + 1, lastI);
    wt[0] = -(1.0f - f); wt[1] = -f;
    c  = g + K;
    ix = fminf(fmaxf((c + 1.0f) * scale, 0.0f), (float)lastI);
    fl = floorf(ix);
    i0 = (int)fl;
    f  = ix - fl;
    idx[2] = i0; idx[3] = min(i0 + 1, lastI);
    wt[2] = 1.0f - f; wt[3] = f;
}

__global__ __launch_bounds__(512, 4) void k_sample(const float* __restrict__ sat,
                                                   const float* __restrict__ ks,
                                                   const float* __restrict__ stats,
                                                   float* __restrict__ out) {
    extern __shared__ float4 tile[];       // 78608 B dynamic -> 2 blocks/CU
    // 4096 blocks -> XCD-contiguous swizzle (512 per XCD)
    const int bid = (blockIdx.x & 7) * 512 + (blockIdx.x >> 3);
    const int tx = bid & 15, ty = (bid >> 4) & 15, tz = (bid >> 8) & 7;
    const int n  = bid >> 11;
    const int x0 = tx * 8, y0 = ty * 8, z0 = tz * 8;
    const int rx0 = x0 - 5, ry0 = y0 - 5, rz0 = z0 - 5;

    const float* satn = sat + (size_t)n * (DHW * 4);   // [z][c][H][W]

    // ---- voxel coords + ks load issued first (latency overlap) ----
    const int v = (int)threadIdx.x;
    const int x = x0 + (v & 7);
    const int y = y0 + ((v >> 3) & 7);
    const int z = z0 + (v >> 6);
    const float* kp = ks + (size_t)(((n * D + z) * H + y) * W + x) * 3;
    const float k0 = kp[0], k1 = kp[1], k2 = kp[2];

    // ---- stage: one (x,y) column per thread; z-prefix accumulated in VGPR.
    // Planar SAT: 4 scalar coalesced loads per slice (consecutive threads ->
    // consecutive addresses within each channel plane).
    for (int col = threadIdx.x; col < RXY; col += 512) {
        const int ry = col / RX, rx = col - ry * RX;
        const int gy = min(max(ry0 + ry, 0), H - 1);
        const int gx = min(max(rx0 + rx, 0), W - 1);
        const float* srcp = satn + ((size_t)gy * W + gx);
        float4 run = {0, 0, 0, 0};
        #pragma unroll
        for (int j = 0; j < RX; ++j) {
            const int gz = min(max(rz0 + j, 0), D - 1);
            const float* sp = srcp + (size_t)gz * (4 * HW);
            run.x += sp[0];
            run.y += sp[HW];
            run.z += sp[2 * HW];
            run.w += sp[3 * HW];
            tile[j * RXY + col] = run;
        }
    }

    // ---- tap math (pure VALU) before the barrier: overlaps staging drain ----
    const float gx = -1.0f + (float)x * (2.0f / 127.0f) - (1.0f / 128.0f);
    const float gy = -1.0f + (float)y * (2.0f / 127.0f) - (1.0f / 128.0f);
    const float gz = -1.0f + (float)z * (2.0f / 63.0f)  - (1.0f / 64.0f);

    int xi[4], yi[4], zi[4];
    float wx[4], wy[4], wz[4];
    taps4(gx, k0 * (1.0f / 128.0f), 63.5f, 127, xi, wx);
    taps4(gy, k1 * (1.0f / 128.0f), 63.5f, 127, yi, wy);
    taps4(gz, k2 * (1.0f / 64.0f),  31.5f,  63, zi, wz);

    // separable count factors (taps applied to the ones-SAT (i+1)(j+1)(k+1))
    const float cx = wx[0] * (float)(xi[0] + 1) + wx[1] * (float)(xi[1] + 1)
                   + wx[2] * (float)(xi[2] + 1) + wx[3] * (float)(xi[3] + 1);
    const float cy = wy[0] * (float)(yi[0] + 1) + wy[1] * (float)(yi[1] + 1)
                   + wy[2] * (float)(yi[2] + 1) + wy[3] * (float)(yi[3] + 1);
    const float cz = wz[0] * (float)(zi[0] + 1) + wz[1] * (float)(zi[1] + 1)
                   + wz[2] * (float)(zi[2] + 1) + wz[3] * (float)(zi[3] + 1);
    const float cnt = cx * cy * cz;

    const int jx0 = xi[0] - rx0, jx1 = xi[1] - rx0;
    const int jx2 = xi[2] - rx0, jx3 = xi[3] - rx0;
    const f32x2 w0 = {wx[0], wx[0]}, w1 = {wx[1], wx[1]};
    const f32x2 w2 = {wx[2], wx[2]}, w3 = {wx[3], wx[3]};

    __syncthreads();

    f32x2 aL = {0, 0}, aH = {0, 0};        // channels {0,1}, {2,3}
    #pragma unroll
    for (int vv = 0; vv < 4; ++vv) {
        const int   zb  = (zi[vv] - rz0) * RXY;
        const float wzv = wz[vv];
        #pragma unroll
        for (int u = 0; u < 4; ++u) {
            const int rb = zb + (yi[u] - ry0) * RX;
            float4 t0 = tile[rb + jx0];
            float4 t1 = tile[rb + jx1];
            float4 t2 = tile[rb + jx2];
            float4 t3 = tile[rb + jx3];
            f32x2 sL = w0 * f32x2{t0.x, t0.y} + w1 * f32x2{t1.x, t1.y}
                     + w2 * f32x2{t2.x, t2.y} + w3 * f32x2{t3.x, t3.y};
            f32x2 sH = w0 * f32x2{t0.z, t0.w} + w1 * f32x2{t1.z, t1.w}
                     + w2 * f32x2{t2.z, t2.w} + w3 * f32x2{t3.z, t3.w};
            const float wvu = wzv * wy[u];
            const f32x2 ww = {wvu, wvu};
            aL += ww * sL;
            aH += ww * sH;
        }
    }

    // out_c = (T_c - mean_c*cnt) * e_c * inva + mean_c
    const float inva = 1.0f / (k0 * k1 * k2 + EPSf);
    const float4 m4 = *(const float4*)(stats + n * 4);
    const float4 e4 = *(const float4*)(stats + 8 + n * 4);
    const int sb = n * C;
    float* po = out + (size_t)sb * DHW + (size_t)z * HW + y * W + x;
    po[0]               = (aL.x - m4.x * cnt) * (e4.x * inva) + m4.x;
    po[DHW]             = (aL.y - m4.y * cnt) * (e4.y * inva) + m4.y;
    po[2 * (size_t)DHW] = (aH.x - m4.z * cnt) * (e4.z * inva) + m4.z;
    po[3 * (size_t)DHW] = (aH.y - m4.w * cnt) * (e4.w * inva) + m4.w;
}

extern "C" void kernel_launch(void* const* d_in, const int* in_sizes, int n_in,
                              void* d_out, int out_size, void* d_ws, size_t ws_size,
                              hipStream_t stream) {
    const float* x  = (const float*)d_in[0];
    const float* ks = (const float*)d_in[1];
    float* out = (float*)d_out;
    float* ws  = (float*)d_ws;

    float* sat   = ws;                               // NC*DHW floats, [n][z][c][H][W]
    float* pSw   = ws + (size_t)NC * DHW;            // 512*4
    float* pQw   = pSw + 2048;                       // 512*4
    float* stats = pQw + 2048;                       // 16 floats: mean[8], e[8]

    (void)hipFuncSetAttribute((const void*)k_sample,
                              hipFuncAttributeMaxDynamicSharedMemorySize,
                              RSLOTS * 16);

    k_sat2d <<<NC * D, 256, 0, stream>>>(x, sat, pSw, pQw);
    k_stats <<<NC, 64, 0, stream>>>(pSw, pQw, stats);
    k_sample<<<4096, 512, RSLOTS * 16, stream>>>(sat, ks, stats, out);
}

// Round 10
// 88.123 us; speedup vs baseline: 6.6877x; 1.1232x over previous
//
#include <hip/hip_runtime.h>
#include <math.h>

// Problem shape (fixed by setup_inputs):
//   x:            [N=2, C=4, D=64, H=128, W=128] f32
//   kernel_sizes: [N=2, D=64, H=128, W=128, 3]   f32
//   out:          [N, C, D, H, W] f32
constexpr int N = 2, C = 4, D = 64, H = 128, W = 128;
constexpr int HW  = H * W;        // 16384
constexpr int DHW = D * H * W;    // 1048576
constexpr int NC  = N * C;        // 8
constexpr float EPSf = 1e-5f;

// k_sample tile: 8x8x8 voxels, taps span [c-5, c+4] per dim -> region 17^3
constexpr int RX = 17;
constexpr int RXY = RX * RX;               // 289
constexpr int RSLOTS = RXY * RX;           // 4913 float4 = 78608 B dynamic LDS

typedef __attribute__((ext_vector_type(2))) float f32x2;

// ---------------- Kernel 1: per-z-slice 2D SAT of RAW x + stats partials ----------------
// Output: PLANAR per-channel 2D-SAT, layout [n][z][c][H][W] (coalesced writes).
// Fully vectorized: float4 global loads, float4 LDS tile with group-XOR
// swizzle (g ^= y&7):
//   - load writes: 32 consecutive groups XOR const -> conflict-free
//   - row scan (lane=row): f4-group mod 8 = (g^(y&7))&7 spans all 8 -> 8
//     lanes/bank-group = b128 ideal (conflict-free)
//   - col scan (lane=col): 2 lanes/bank -> free
__global__ __launch_bounds__(256) void k_sat2d(const float* __restrict__ x,
                                               float* __restrict__ sat,
                                               float* __restrict__ pSw,
                                               float* __restrict__ pQw) {
    __shared__ float4 t4[H * 32];          // 65536 B, [y][32 f4-groups] swizzled
    float* tilef = (float*)t4;
    const int slice = blockIdx.x;          // nc*D + z
    const int nc = slice >> 6;
    const int z  = slice & 63;
    const int n  = nc >> 2;
    const int c  = nc & 3;
    const float4* src4 = (const float4*)(x + (size_t)slice * HW);

    float s = 0.f, q = 0.f;
    for (int i = threadIdx.x; i < HW / 4; i += 256) {   // 16 iters
        const int y = i >> 5, g = i & 31;
        float4 v = src4[i];
        s += v.x + v.y + v.z + v.w;
        q += v.x * v.x + v.y * v.y + v.z * v.z + v.w * v.w;
        t4[(y << 5) + (g ^ (y & 7))] = v;
    }
    #pragma unroll
    for (int off = 32; off; off >>= 1) {
        s += __shfl_down(s, off, 64);
        q += __shfl_down(q, off, 64);
    }
    if ((threadIdx.x & 63) == 0) {
        const int w = threadIdx.x >> 6;
        pSw[slice * 4 + w] = s;
        pQw[slice * 4 + w] = q;
    }
    __syncthreads();
    // row scan (x): thread y, 32 b128 iters with in-register 4-prefix
    if (threadIdx.x < H) {
        const int y = threadIdx.x, sw = y & 7;
        float4* rowp = t4 + (y << 5);
        float run = 0.f;
        for (int g = 0; g < 32; ++g) {
            float4 v = rowp[g ^ sw];
            float a = run + v.x;
            float b = a + v.y;
            float cc = b + v.z;
            float d = cc + v.w;
            rowp[g ^ sw] = float4{a, b, cc, d};
            run = d;
        }
    }
    __syncthreads();
    // column scan (y) fused with PLANAR coalesced global write
    if (threadIdx.x < W) {
        const int xx = threadIdx.x;
        const int g = xx >> 2, l = xx & 3;
        float* dst = sat + ((size_t)(n * D + z) * C + c) * HW + xx;
        float run = 0.f;
        for (int y = 0; y < H; ++y) {
            run += tilef[(((y << 5) + (g ^ (y & 7))) << 2) + l];
            dst[(size_t)y * W] = run;
        }
    }
}

// ---------------- Kernel 2: finalize mean / e = std/(std+EPS) ----------------
__global__ __launch_bounds__(64) void k_stats(const float* __restrict__ pSw,
                                              const float* __restrict__ pQw,
                                              float* __restrict__ stats) {
    const int nc = blockIdx.x;
    const int t  = threadIdx.x;            // one of 64 slices of this nc
    const float4 sv = *(const float4*)(pSw + (size_t)(nc * 64 + t) * 4);
    const float4 qv = *(const float4*)(pQw + (size_t)(nc * 64 + t) * 4);
    double s = (double)sv.x + sv.y + sv.z + sv.w;
    double q = (double)qv.x + qv.y + qv.z + qv.w;
    #pragma unroll
    for (int off = 32; off; off >>= 1) {
        s += __shfl_down(s, off, 64);
        q += __shfl_down(q, off, 64);
    }
    if (t == 0) {
        const double M = (double)DHW;
        double mean = s / M;
        double var  = (q - s * s / M) / (M - 1.0);   // torch ddof=1
        float stdv  = (float)sqrt(var);
        stats[nc]     = (float)mean;
        stats[8 + nc] = stdv / (stdv + EPSf);        // e = std/(std+EPS)
    }
}

// ---------------- Kernel 3: LDS-staged thread-per-voxel box sample ----------------
__device__ __forceinline__ void taps4(float g, float K, float scale, int lastI,
                                      int* idx, float* wt) {
    float c  = g - K;
    float ix = fminf(fmaxf((c + 1.0f) * scale, 0.0f), (float)lastI);
    float fl = floorf(ix);
    int   i0 = (int)fl;
    float f  = ix - fl;
    idx[0] = i0; idx[1] = min(i0 + 1, lastI);
    wt[0] = -(1.0f - f); wt[1] = -f;
    c  = g + K;
    ix = fminf(fmaxf((c + 1.0f) * scale, 0.0f), (float)lastI);
    fl = floorf(ix);
    i0 = (int)fl;
    f  = ix - fl;
    idx[2] = i0; idx[3] = min(i0 + 1, lastI);
    wt[2] = 1.0f - f; wt[3] = f;
}

__global__ __launch_bounds__(512, 4) void k_sample(const float* __restrict__ sat,
                                                   const float* __restrict__ ks,
                                                   const float* __restrict__ stats,
                                                   float* __restrict__ out) {
    extern __shared__ float4 tile[];       // 78608 B dynamic -> 2 blocks/CU
    // 4096 blocks -> XCD-contiguous swizzle (512 per XCD)
    const int bid = (blockIdx.x & 7) * 512 + (blockIdx.x >> 3);
    const int tx = bid & 15, ty = (bid >> 4) & 15, tz = (bid >> 8) & 7;
    const int n  = bid >> 11;
    const int x0 = tx * 8, y0 = ty * 8, z0 = tz * 8;
    const int rx0 = x0 - 5, ry0 = y0 - 5, rz0 = z0 - 5;

    const float* satn = sat + (size_t)n * (DHW * 4);   // [z][c][H][W]

    // ---- voxel coords + ks load issued first (latency overlap) ----
    const int v = (int)threadIdx.x;
    const int x = x0 + (v & 7);
    const int y = y0 + ((v >> 3) & 7);
    const int z = z0 + (v >> 6);
    const float* kp = ks + (size_t)(((n * D + z) * H + y) * W + x) * 3;
    const float k0 = kp[0], k1 = kp[1], k2 = kp[2];

    // ---- stage: one (x,y) column per thread; z-prefix accumulated in VGPR.
    // Planar SAT: 4 scalar coalesced loads per slice.
    for (int col = threadIdx.x; col < RXY; col += 512) {
        const int ry = col / RX, rx = col - ry * RX;
        const int gy = min(max(ry0 + ry, 0), H - 1);
        const int gx = min(max(rx0 + rx, 0), W - 1);
        const float* srcp = satn + ((size_t)gy * W + gx);
        float4 run = {0, 0, 0, 0};
        #pragma unroll
        for (int j = 0; j < RX; ++j) {
            const int gz = min(max(rz0 + j, 0), D - 1);
            const float* sp = srcp + (size_t)gz * (4 * HW);
            run.x += sp[0];
            run.y += sp[HW];
            run.z += sp[2 * HW];
            run.w += sp[3 * HW];
            tile[j * RXY + col] = run;
        }
    }

    // ---- tap math (pure VALU) before the barrier: overlaps staging drain ----
    const float gx = -1.0f + (float)x * (2.0f / 127.0f) - (1.0f / 128.0f);
    const float gy = -1.0f + (float)y * (2.0f / 127.0f) - (1.0f / 128.0f);
    const float gz = -1.0f + (float)z * (2.0f / 63.0f)  - (1.0f / 64.0f);

    int xi[4], yi[4], zi[4];
    float wx[4], wy[4], wz[4];
    taps4(gx, k0 * (1.0f / 128.0f), 63.5f, 127, xi, wx);
    taps4(gy, k1 * (1.0f / 128.0f), 63.5f, 127, yi, wy);
    taps4(gz, k2 * (1.0f / 64.0f),  31.5f,  63, zi, wz);

    // separable count factors (taps applied to the ones-SAT (i+1)(j+1)(k+1))
    const float cx = wx[0] * (float)(xi[0] + 1) + wx[1] * (float)(xi[1] + 1)
                   + wx[2] * (float)(xi[2] + 1) + wx[3] * (float)(xi[3] + 1);
    const float cy = wy[0] * (float)(yi[0] + 1) + wy[1] * (float)(yi[1] + 1)
                   + wy[2] * (float)(yi[2] + 1) + wy[3] * (float)(yi[3] + 1);
    const float cz = wz[0] * (float)(zi[0] + 1) + wz[1] * (float)(zi[1] + 1)
                   + wz[2] * (float)(zi[2] + 1) + wz[3] * (float)(zi[3] + 1);
    const float cnt = cx * cy * cz;

    const int jx0 = xi[0] - rx0, jx1 = xi[1] - rx0;
    const int jx2 = xi[2] - rx0, jx3 = xi[3] - rx0;
    const f32x2 w0 = {wx[0], wx[0]}, w1 = {wx[1], wx[1]};
    const f32x2 w2 = {wx[2], wx[2]}, w3 = {wx[3], wx[3]};

    __syncthreads();

    f32x2 aL = {0, 0}, aH = {0, 0};        // channels {0,1}, {2,3}
    #pragma unroll
    for (int vv = 0; vv < 4; ++vv) {
        const int   zb  = (zi[vv] - rz0) * RXY;
        const float wzv = wz[vv];
        #pragma unroll
        for (int u = 0; u < 4; ++u) {
            const int rb = zb + (yi[u] - ry0) * RX;
            float4 t0 = tile[rb + jx0];
            float4 t1 = tile[rb + jx1];
            float4 t2 = tile[rb + jx2];
            float4 t3 = tile[rb + jx3];
            f32x2 sL = w0 * f32x2{t0.x, t0.y} + w1 * f32x2{t1.x, t1.y}
                     + w2 * f32x2{t2.x, t2.y} + w3 * f32x2{t3.x, t3.y};
            f32x2 sH = w0 * f32x2{t0.z, t0.w} + w1 * f32x2{t1.z, t1.w}
                     + w2 * f32x2{t2.z, t2.w} + w3 * f32x2{t3.z, t3.w};
            const float wvu = wzv * wy[u];
            const f32x2 ww = {wvu, wvu};
            aL += ww * sL;
            aH += ww * sH;
        }
    }

    // out_c = (T_c - mean_c*cnt) * e_c * inva + mean_c
    const float inva = 1.0f / (k0 * k1 * k2 + EPSf);
    const float4 m4 = *(const float4*)(stats + n * 4);
    const float4 e4 = *(const float4*)(stats + 8 + n * 4);
    const int sb = n * C;
    float* po = out + (size_t)sb * DHW + (size_t)z * HW + y * W + x;
    po[0]               = (aL.x - m4.x * cnt) * (e4.x * inva) + m4.x;
    po[DHW]             = (aL.y - m4.y * cnt) * (e4.y * inva) + m4.y;
    po[2 * (size_t)DHW] = (aH.x - m4.z * cnt) * (e4.z * inva) + m4.z;
    po[3 * (size_t)DHW] = (aH.y - m4.w * cnt) * (e4.w * inva) + m4.w;
}

extern "C" void kernel_launch(void* const* d_in, const int* in_sizes, int n_in,
                              void* d_out, int out_size, void* d_ws, size_t ws_size,
                              hipStream_t stream) {
    const float* x  = (const float*)d_in[0];
    const float* ks = (const float*)d_in[1];
    float* out = (float*)d_out;
    float* ws  = (float*)d_ws;

    float* sat   = ws;                               // NC*DHW floats, [n][z][c][H][W]
    float* pSw   = ws + (size_t)NC * DHW;            // 512*4
    float* pQw   = pSw + 2048;                       // 512*4
    float* stats = pQw + 2048;                       // 16 floats: mean[8], e[8]

    (void)hipFuncSetAttribute((const void*)k_sample,
                              hipFuncAttributeMaxDynamicSharedMemorySize,
                              RSLOTS * 16);

    k_sat2d <<<NC * D, 256, 0, stream>>>(x, sat, pSw, pQw);
    k_stats <<<NC, 64, 0, stream>>>(pSw, pQw, stats);
    k_sample<<<4096, 512, RSLOTS * 16, stream>>>(sat, ks, stats, out);
}